// Round 4
// baseline (759.108 us; speedup 1.0000x reference)
//
#include <hip/hip_runtime.h>
#include <hip/hip_bf16.h>

// ---------------------------------------------------------------------------
// GIN forward. Pipeline (all fp32):
//   CSR build (dst adjacency) once per call
//   K1: y1 = x @ W1a                         (K=128, uniform-A GEMM)
//   K2: zin1 = relu(y1 + gather(y1) + b1a)
//   K3: h1 = relu(zin1 @ W1b + b1b)
//   K4: y2 = h1 @ W2a
//   K5: zin2 = relu(y2 + gather(y2) + b2a)
//   K6: gemm_pool: relu(zin2@W2b + b2b).fcW -> segmented atomicAdd per graph
//   K7: out[g] = gacc[g]/cnt[g] + fcb
// GEMM layout: 64-row tile, 256 thr = 4 waves, lane = output column.
// A operands are wave-uniform global loads (scalarized); W in LDS b32 reads.
// ---------------------------------------------------------------------------

#define NODES 200000
#define EDGES 200000
#define GRAPHS 2048
#define NB_SCAN 782   // ceil(NODES/256)

// ---------------- CSR build ----------------
__global__ __launch_bounds__(256) void count_k(
    const int* __restrict__ ei, int* __restrict__ cnt, int E)
{
    int e = blockIdx.x * 256 + threadIdx.x;
    if (e < E) atomicAdd(&cnt[ei[E + e]], 1);
}

__global__ __launch_bounds__(256) void scan1_k(
    const int* __restrict__ cnt, int* __restrict__ excl,
    int* __restrict__ bsum, int N)
{
    __shared__ int sh[256];
    int tid = threadIdx.x;
    int i = blockIdx.x * 256 + tid;
    int v = (i < N) ? cnt[i] : 0;
    sh[tid] = v;
    __syncthreads();
    for (int off = 1; off < 256; off <<= 1) {
        int t = (tid >= off) ? sh[tid - off] : 0;
        __syncthreads();
        sh[tid] += t;
        __syncthreads();
    }
    if (i < N) excl[i] = sh[tid] - v;
    if (tid == 255) bsum[blockIdx.x] = sh[255];
}

__global__ __launch_bounds__(1024) void scan2_k(int* __restrict__ bsum, int NB)
{
    __shared__ int sh[1024];
    int tid = threadIdx.x;
    int v = (tid < NB) ? bsum[tid] : 0;
    sh[tid] = v;
    __syncthreads();
    for (int off = 1; off < 1024; off <<= 1) {
        int t = (tid >= off) ? sh[tid - off] : 0;
        __syncthreads();
        sh[tid] += t;
        __syncthreads();
    }
    if (tid < NB) bsum[tid] = sh[tid] - v;
}

__global__ __launch_bounds__(256) void scan3_k(
    int* __restrict__ rowptr, const int* __restrict__ bsum,
    int* __restrict__ cursor, int N, int E)
{
    int i = blockIdx.x * 256 + threadIdx.x;
    if (i < N) {
        int v = rowptr[i] + bsum[blockIdx.x];
        rowptr[i] = v;
        cursor[i] = v;
    }
    if (i == 0) rowptr[N] = E;
}

__global__ __launch_bounds__(256) void fill_k(
    const int* __restrict__ ei, int* __restrict__ cursor,
    int* __restrict__ srcs, int E)
{
    int e = blockIdx.x * 256 + threadIdx.x;
    if (e < E) {
        int d = ei[E + e];
        int p = atomicAdd(&cursor[d], 1);
        srcs[p] = ei[e];
    }
}

// ---------------- uniform-A GEMM core ----------------
// One wave handles 16 rows x 64 cols (lane = col). acc[16] per lane.
// A[row][k4*4..+3] is the same address for all 64 lanes -> scalar/broadcast.
template<int K>
__device__ __forceinline__ void gemmU_core(
    const float* __restrict__ Ab,   // base of this wave's 16 rows
    const float* __restrict__ Ws,   // [K][64] in LDS
    int lane, float acc[16])
{
    for (int k4 = 0; k4 < K / 4; ++k4) {
        const int k = k4 * 4;
        float w0 = Ws[(k + 0) * 64 + lane];
        float w1 = Ws[(k + 1) * 64 + lane];
        float w2 = Ws[(k + 2) * 64 + lane];
        float w3 = Ws[(k + 3) * 64 + lane];
        #pragma unroll
        for (int rg = 0; rg < 4; ++rg) {
            const float* Ar = Ab + (size_t)(rg * 4) * K + k;
            float4 a0 = *reinterpret_cast<const float4*>(Ar);
            float4 a1 = *reinterpret_cast<const float4*>(Ar + K);
            float4 a2 = *reinterpret_cast<const float4*>(Ar + 2 * K);
            float4 a3 = *reinterpret_cast<const float4*>(Ar + 3 * K);
            float* ac = acc + rg * 4;
            ac[0] = fmaf(a0.x, w0, ac[0]);
            ac[0] = fmaf(a0.y, w1, ac[0]);
            ac[0] = fmaf(a0.z, w2, ac[0]);
            ac[0] = fmaf(a0.w, w3, ac[0]);
            ac[1] = fmaf(a1.x, w0, ac[1]);
            ac[1] = fmaf(a1.y, w1, ac[1]);
            ac[1] = fmaf(a1.z, w2, ac[1]);
            ac[1] = fmaf(a1.w, w3, ac[1]);
            ac[2] = fmaf(a2.x, w0, ac[2]);
            ac[2] = fmaf(a2.y, w1, ac[2]);
            ac[2] = fmaf(a2.z, w2, ac[2]);
            ac[2] = fmaf(a2.w, w3, ac[2]);
            ac[3] = fmaf(a3.x, w0, ac[3]);
            ac[3] = fmaf(a3.y, w1, ac[3]);
            ac[3] = fmaf(a3.z, w2, ac[3]);
            ac[3] = fmaf(a3.w, w3, ac[3]);
        }
    }
}

// out[N,64] = opt_relu(A[N,K] @ W[K,64] + opt_bias)
template<int K, bool BIAS, bool RELU>
__global__ __launch_bounds__(256) void gemmU_k(
    const float* __restrict__ A, const float* __restrict__ W,
    const float* __restrict__ bias, float* __restrict__ out, int N)
{
    __shared__ float Ws[K * 64];
    const int tid = threadIdx.x;
    for (int i = tid; i < K * 16; i += 256)
        reinterpret_cast<float4*>(Ws)[i] = reinterpret_cast<const float4*>(W)[i];
    __syncthreads();

    const int lane = tid & 63;
    const int row0 = blockIdx.x * 64 + (tid >> 6) * 16;

    float acc[16];
    #pragma unroll
    for (int r = 0; r < 16; ++r) acc[r] = 0.f;

    gemmU_core<K>(A + (size_t)row0 * K, Ws, lane, acc);

    const float bv = BIAS ? bias[lane] : 0.f;
    #pragma unroll
    for (int r = 0; r < 16; ++r) {
        float v = acc[r] + bv;
        if (RELU) v = fmaxf(v, 0.f);
        out[(size_t)(row0 + r) * 64 + lane] = v;
    }
}

// relu(A@W + b).fcW, segment-reduced over sorted batch, one atomic per segment
__global__ __launch_bounds__(256) void gemm_pool_k(
    const float* __restrict__ A, const float* __restrict__ W,
    const float* __restrict__ bias, const float* __restrict__ fcW,
    const int* __restrict__ batch, float* __restrict__ gacc, int N)
{
    __shared__ float Ws[64 * 64];
    const int tid = threadIdx.x;
    for (int i = tid; i < 64 * 16; i += 256)
        reinterpret_cast<float4*>(Ws)[i] = reinterpret_cast<const float4*>(W)[i];
    __syncthreads();

    const int lane = tid & 63;
    const int row0 = blockIdx.x * 64 + (tid >> 6) * 16;

    float acc[16];
    #pragma unroll
    for (int r = 0; r < 16; ++r) acc[r] = 0.f;

    gemmU_core<64>(A + (size_t)row0 * 64, Ws, lane, acc);

    const float bv = bias[lane];
    const float fw = fcW[lane];

    int curg = -1;
    float part = 0.f;
    #pragma unroll
    for (int r = 0; r < 16; ++r) {
        int g = batch[row0 + r];               // wave-uniform
        float v = fmaxf(acc[r] + bv, 0.f) * fw;
        if (g != curg) {
            if (curg >= 0) {
                float t = part;
                t += __shfl_xor(t, 32);
                t += __shfl_xor(t, 16);
                t += __shfl_xor(t, 8);
                t += __shfl_xor(t, 4);
                t += __shfl_xor(t, 2);
                t += __shfl_xor(t, 1);
                if (lane == 0) atomicAdd(&gacc[curg], t);
            }
            curg = g;
            part = 0.f;
        }
        part += v;
    }
    {
        float t = part;
        t += __shfl_xor(t, 32);
        t += __shfl_xor(t, 16);
        t += __shfl_xor(t, 8);
        t += __shfl_xor(t, 4);
        t += __shfl_xor(t, 2);
        t += __shfl_xor(t, 1);
        if (lane == 0) atomicAdd(&gacc[curg], t);
    }
}

// ---------------- aggregation: zin[n] = relu(y[n] + sum_{s in N(n)} y[s] + b) -
__global__ __launch_bounds__(256) void agg_relu_k(
    const float* __restrict__ y, const int* __restrict__ rowptr,
    const int* __restrict__ srcs, const float* __restrict__ bias,
    float* __restrict__ zin, int N)
{
    int t = blockIdx.x * 256 + threadIdx.x;
    int node = t >> 4;
    if (node >= N) return;
    int c = (t & 15) * 4;

    int s0 = rowptr[node];
    int s1 = rowptr[node + 1];

    float4 acc = *reinterpret_cast<const float4*>(y + (size_t)node * 64 + c);
    float4 b4 = *reinterpret_cast<const float4*>(bias + c);
    acc.x += b4.x; acc.y += b4.y; acc.z += b4.z; acc.w += b4.w;

    for (int j = s0; j < s1; ++j) {
        int s = srcs[j];
        float4 vv = *reinterpret_cast<const float4*>(y + (size_t)s * 64 + c);
        acc.x += vv.x; acc.y += vv.y; acc.z += vv.z; acc.w += vv.w;
    }

    float4 o;
    o.x = fmaxf(acc.x, 0.f);
    o.y = fmaxf(acc.y, 0.f);
    o.z = fmaxf(acc.z, 0.f);
    o.w = fmaxf(acc.w, 0.f);
    *reinterpret_cast<float4*>(zin + (size_t)node * 64 + c) = o;
}

// ---------------- finalize: out[g] = gacc[g]/cnt[g] + fcb ----------------
__global__ __launch_bounds__(256) void finalize_k(
    const float* __restrict__ gacc, const int* __restrict__ batch,
    const float* __restrict__ fcb, float* __restrict__ out, int N, int G)
{
    int g = blockIdx.x * 256 + threadIdx.x;
    if (g >= G) return;
    int lo = 0, hi = N;
    while (lo < hi) { int m = (lo + hi) >> 1; if (batch[m] < g) lo = m + 1; else hi = m; }
    int start = lo;
    hi = N;
    while (lo < hi) { int m = (lo + hi) >> 1; if (batch[m] < g + 1) lo = m + 1; else hi = m; }
    float cnt = fmaxf((float)(lo - start), 1.f);
    out[g] = gacc[g] / cnt + fcb[0];
}

extern "C" void kernel_launch(void* const* d_in, const int* in_sizes, int n_in,
                              void* d_out, int out_size, void* d_ws, size_t ws_size,
                              hipStream_t stream)
{
    const float* x     = (const float*)d_in[0];
    const int*   ei    = (const int*)d_in[1];   // [2, E]
    const int*   batch = (const int*)d_in[2];   // [N], sorted
    const float* W1a   = (const float*)d_in[3];
    const float* b1a   = (const float*)d_in[4];
    const float* W1b   = (const float*)d_in[5];
    const float* b1b   = (const float*)d_in[6];
    const float* W2a   = (const float*)d_in[7];
    const float* b2a   = (const float*)d_in[8];
    const float* W2b   = (const float*)d_in[9];
    const float* b2b   = (const float*)d_in[10];
    const float* fcW   = (const float*)d_in[11];
    const float* fcb   = (const float*)d_in[12];
    float* out = (float*)d_out;

    const int N = NODES, E = EDGES, G = GRAPHS;
    char* ws = (char*)d_ws;
    const size_t szH = (size_t)N * 64 * sizeof(float);   // 51.2 MB

    float* yBuf   = (float*)ws;                 // [0, 51.2)
    float* zinBuf = (float*)(ws + szH);         // [51.2, 102.4)
    float* hBuf   = (float*)(ws + 2 * szH);     // [102.4, 153.6)
    char*  rest   = ws + 3 * szH;
    int* cnt    = (int*)rest;           // N
    int* rowptr = cnt + NODES;          // N+1
    int* cursor = rowptr + NODES + 1;   // N
    int* srcs   = cursor + NODES;       // E
    int* bsum   = srcs + EDGES;         // NB_SCAN
    float* gacc = (float*)(bsum + NB_SCAN + 2);

    // ---- CSR build ----
    hipMemsetAsync(cnt, 0, (size_t)N * sizeof(int), stream);
    hipMemsetAsync(gacc, 0, (size_t)G * sizeof(float), stream);
    count_k<<<NB_SCAN, 256, 0, stream>>>(ei, cnt, E);
    scan1_k<<<NB_SCAN, 256, 0, stream>>>(cnt, rowptr, bsum, N);
    scan2_k<<<1, 1024, 0, stream>>>(bsum, NB_SCAN);
    scan3_k<<<NB_SCAN, 256, 0, stream>>>(rowptr, bsum, cursor, N, E);
    fill_k<<<NB_SCAN, 256, 0, stream>>>(ei, cursor, srcs, E);

    // ---- layer 1 ----
    gemmU_k<128, false, false><<<N / 64, 256, 0, stream>>>(x, W1a, nullptr, yBuf, N);
    agg_relu_k<<<N * 16 / 256, 256, 0, stream>>>(yBuf, rowptr, srcs, b1a, zinBuf, N);
    gemmU_k<64, true, true><<<N / 64, 256, 0, stream>>>(zinBuf, W1b, b1b, hBuf, N);

    // ---- layer 2 ----
    gemmU_k<64, false, false><<<N / 64, 256, 0, stream>>>(hBuf, W2a, nullptr, yBuf, N);
    agg_relu_k<<<N * 16 / 256, 256, 0, stream>>>(yBuf, rowptr, srcs, b2a, zinBuf, N);

    // ---- h2 GEMM fused with pool/fc ----
    gemm_pool_k<<<N / 64, 256, 0, stream>>>(zinBuf, W2b, b2b, fcW, batch, gacc, N);
    finalize_k<<<(G + 255) / 256, 256, 0, stream>>>(gacc, batch, fcb, out, N, G);
}

// Round 5
// 334.635 us; speedup vs baseline: 2.2685x; 2.2685x over previous
//
#include <hip/hip_runtime.h>
#include <hip/hip_bf16.h>

// ---------------------------------------------------------------------------
// GIN forward with split-bf16 MFMA GEMMs (fp32-accurate):
//   A = hi + lo (bf16 each);  A@W ≈ hi@Whi + lo@Whi + hi@Wlo  (3 MFMA)
//   product rel-err ~2^-17, fp32 MFMA accumulation -> ~fp32 precision.
// Pipeline:
//   CSR build once;  mm1: y1 = x@W1a (K=128)
//   agg: zin1 = relu(y1 + gather(y1) + b1a)
//   mm: h1 = relu(zin1@W1b + b1b);  mm: y2 = h1@W2a
//   agg: zin2 = relu(y2 + gather(y2) + b2a)
//   mm_pool: relu(zin2@W2b+b2b).fcW -> segmented atomics;  finalize
// ---------------------------------------------------------------------------

#define NODES 200000
#define EDGES 200000
#define GRAPHS 2048
#define NB_SCAN 782   // ceil(NODES/256)

typedef __attribute__((ext_vector_type(8))) short short8;
typedef __attribute__((ext_vector_type(4))) float f32x4;

__device__ __forceinline__ unsigned short f2bf(float f) {
    unsigned u = __builtin_bit_cast(unsigned, f);
    u = (u + 0x7fffu + ((u >> 16) & 1u)) >> 16;
    return (unsigned short)u;
}
__device__ __forceinline__ float bf2f(unsigned short h) {
    unsigned u = ((unsigned)h) << 16;
    return __builtin_bit_cast(float, u);
}

// ---------------- CSR build ----------------
__global__ __launch_bounds__(256) void count_k(
    const int* __restrict__ ei, int* __restrict__ cnt, int E)
{
    int e = blockIdx.x * 256 + threadIdx.x;
    if (e < E) atomicAdd(&cnt[ei[E + e]], 1);
}

__global__ __launch_bounds__(256) void scan1_k(
    const int* __restrict__ cnt, int* __restrict__ excl,
    int* __restrict__ bsum, int N)
{
    __shared__ int sh[256];
    int tid = threadIdx.x;
    int i = blockIdx.x * 256 + tid;
    int v = (i < N) ? cnt[i] : 0;
    sh[tid] = v;
    __syncthreads();
    for (int off = 1; off < 256; off <<= 1) {
        int t = (tid >= off) ? sh[tid - off] : 0;
        __syncthreads();
        sh[tid] += t;
        __syncthreads();
    }
    if (i < N) excl[i] = sh[tid] - v;
    if (tid == 255) bsum[blockIdx.x] = sh[255];
}

__global__ __launch_bounds__(1024) void scan2_k(int* __restrict__ bsum, int NB)
{
    __shared__ int sh[1024];
    int tid = threadIdx.x;
    int v = (tid < NB) ? bsum[tid] : 0;
    sh[tid] = v;
    __syncthreads();
    for (int off = 1; off < 1024; off <<= 1) {
        int t = (tid >= off) ? sh[tid - off] : 0;
        __syncthreads();
        sh[tid] += t;
        __syncthreads();
    }
    if (tid < NB) bsum[tid] = sh[tid] - v;
}

__global__ __launch_bounds__(256) void scan3_k(
    int* __restrict__ rowptr, const int* __restrict__ bsum,
    int* __restrict__ cursor, int N, int E)
{
    int i = blockIdx.x * 256 + threadIdx.x;
    if (i < N) {
        int v = rowptr[i] + bsum[blockIdx.x];
        rowptr[i] = v;
        cursor[i] = v;
    }
    if (i == 0) rowptr[N] = E;
}

__global__ __launch_bounds__(256) void fill_k(
    const int* __restrict__ ei, int* __restrict__ cursor,
    int* __restrict__ srcs, int E)
{
    int e = blockIdx.x * 256 + threadIdx.x;
    if (e < E) {
        int d = ei[E + e];
        int p = atomicAdd(&cursor[d], 1);
        srcs[p] = ei[e];
    }
}

// ---------------- split-bf16 MFMA GEMM pieces ----------------
// W fragments in LDS: Wf[h][kc][nb][lane][j], h=0 hi / h=1 lo.
// frag element: k = kc*32 + (lane>>4)*8 + j, col = nb*16 + (lane&15).
template<int KC>
__device__ __forceinline__ void fill_wfrags(
    const float* __restrict__ W, short* __restrict__ Wf, int tid)
{
    for (int e = tid; e < KC * 4 * 64; e += 256) {
        int lane = e & 63;
        int nb = (e >> 6) & 3;
        int kc = e >> 8;
        int col = nb * 16 + (lane & 15);
        int kb = kc * 32 + ((lane >> 4) * 8);
        short8 hi, lo;
        #pragma unroll
        for (int j = 0; j < 8; ++j) {
            float w = W[(size_t)(kb + j) * 64 + col];
            unsigned short h = f2bf(w);
            float r = w - bf2f(h);
            hi[j] = (short)h;
            lo[j] = (short)f2bf(r);
        }
        *reinterpret_cast<short8*>(Wf + (size_t)e * 8) = hi;
        *reinterpret_cast<short8*>(Wf + ((size_t)(KC * 4 * 64) + e) * 8) = lo;
    }
}

__device__ __forceinline__ void cvt_a8(const float av[8], short8& hi, short8& lo)
{
    #pragma unroll
    for (int j = 0; j < 8; ++j) {
        unsigned short h = f2bf(av[j]);
        float r = av[j] - bf2f(h);
        hi[j] = (short)h;
        lo[j] = (short)f2bf(r);
    }
}

// core K-loop: acc[nb] over 4 col-blocks; A from global (row0w = wave row base)
template<int K>
__device__ __forceinline__ void mm_core(
    const float* __restrict__ A, const short* __restrict__ Wf,
    int row0w, int lane, f32x4 acc[4])
{
    constexpr int KC = K / 32;
    const float* Ar = A + (size_t)(row0w + (lane & 15)) * K;
    #pragma unroll
    for (int kc = 0; kc < KC; ++kc) {
        const int kb = kc * 32 + ((lane >> 4) * 8);
        float4 a0 = *reinterpret_cast<const float4*>(Ar + kb);
        float4 a1 = *reinterpret_cast<const float4*>(Ar + kb + 4);
        float av[8] = {a0.x, a0.y, a0.z, a0.w, a1.x, a1.y, a1.z, a1.w};
        short8 ahi, alo;
        cvt_a8(av, ahi, alo);
        #pragma unroll
        for (int nb = 0; nb < 4; ++nb) {
            const short8 whi = *reinterpret_cast<const short8*>(
                Wf + ((size_t)((kc * 4 + nb) * 64) + lane) * 8);
            const short8 wlo = *reinterpret_cast<const short8*>(
                Wf + ((size_t)((KC * 4 + kc * 4 + nb) * 64) + lane) * 8);
            acc[nb] = __builtin_amdgcn_mfma_f32_16x16x32_bf16(ahi, whi, acc[nb], 0, 0, 0);
            acc[nb] = __builtin_amdgcn_mfma_f32_16x16x32_bf16(alo, whi, acc[nb], 0, 0, 0);
            acc[nb] = __builtin_amdgcn_mfma_f32_16x16x32_bf16(ahi, wlo, acc[nb], 0, 0, 0);
        }
    }
}

// out[N,64] = opt_relu(A[N,K] @ W[K,64] + opt_bias)
template<int K, bool BIAS, bool RELU>
__global__ __launch_bounds__(256) void mm_k(
    const float* __restrict__ A, const float* __restrict__ W,
    const float* __restrict__ bias, float* __restrict__ out, int N)
{
    constexpr int KC = K / 32;
    __shared__ short Wf[2 * KC * 4 * 64 * 8];
    const int tid = threadIdx.x;
    fill_wfrags<KC>(W, Wf, tid);
    __syncthreads();

    const int lane = tid & 63;
    const int row0w = blockIdx.x * 64 + (tid >> 6) * 16;

    f32x4 acc[4] = {{0.f, 0.f, 0.f, 0.f}, {0.f, 0.f, 0.f, 0.f},
                    {0.f, 0.f, 0.f, 0.f}, {0.f, 0.f, 0.f, 0.f}};
    mm_core<K>(A, Wf, row0w, lane, acc);

    const int grp = lane >> 4, c = lane & 15;
    #pragma unroll
    for (int nb = 0; nb < 4; ++nb) {
        const int col = nb * 16 + c;
        const float bv = BIAS ? bias[col] : 0.f;
        #pragma unroll
        for (int reg = 0; reg < 4; ++reg) {
            const int orow = row0w + grp * 4 + reg;
            float v = acc[nb][reg] + bv;
            if (RELU) v = fmaxf(v, 0.f);
            out[(size_t)orow * 64 + col] = v;
        }
    }
}

// relu(A@W + b).fcW -> segmented (sorted batch) atomicAdd per graph
__global__ __launch_bounds__(256) void mm_pool_k(
    const float* __restrict__ A, const float* __restrict__ W,
    const float* __restrict__ bias, const float* __restrict__ fcW,
    const int* __restrict__ batch, float* __restrict__ gacc, int N)
{
    constexpr int KC = 2;   // K=64
    __shared__ short Wf[2 * KC * 4 * 64 * 8];
    __shared__ float rd[4][16];
    __shared__ int bls[4][16];
    const int tid = threadIdx.x;
    fill_wfrags<KC>(W, Wf, tid);
    __syncthreads();

    const int lane = tid & 63;
    const int wv = tid >> 6;
    const int row0w = blockIdx.x * 64 + wv * 16;

    f32x4 acc[4] = {{0.f, 0.f, 0.f, 0.f}, {0.f, 0.f, 0.f, 0.f},
                    {0.f, 0.f, 0.f, 0.f}, {0.f, 0.f, 0.f, 0.f}};
    mm_core<64>(A, Wf, row0w, lane, acc);

    const int grp = lane >> 4, c = lane & 15;
    float bv[4], fw[4];
    #pragma unroll
    for (int nb = 0; nb < 4; ++nb) {
        bv[nb] = bias[nb * 16 + c];
        fw[nb] = fcW[nb * 16 + c];
    }
    if (c < 16 && grp == 0) { /* no-op, keep structure */ }
    if (lane < 16) bls[wv][lane] = batch[row0w + lane];

    #pragma unroll
    for (int reg = 0; reg < 4; ++reg) {
        float t = 0.f;
        #pragma unroll
        for (int nb = 0; nb < 4; ++nb)
            t += fmaxf(acc[nb][reg] + bv[nb], 0.f) * fw[nb];
        t += __shfl_xor(t, 1, 16);
        t += __shfl_xor(t, 2, 16);
        t += __shfl_xor(t, 4, 16);
        t += __shfl_xor(t, 8, 16);
        if (c == 0) rd[wv][grp * 4 + reg] = t;   // row-dot for row row0w+grp*4+reg
    }

    if (lane == 0) {
        int curg = bls[wv][0];
        float s = rd[wv][0];
        #pragma unroll
        for (int i = 1; i < 16; ++i) {
            int g = bls[wv][i];
            float v = rd[wv][i];
            if (g == curg) s += v;
            else { atomicAdd(&gacc[curg], s); curg = g; s = v; }
        }
        atomicAdd(&gacc[curg], s);
    }
}

// ---------------- aggregation: zin[n] = relu(y[n] + sum_{s in N(n)} y[s] + b) -
__global__ __launch_bounds__(256) void agg_relu_k(
    const float* __restrict__ y, const int* __restrict__ rowptr,
    const int* __restrict__ srcs, const float* __restrict__ bias,
    float* __restrict__ zin, int N)
{
    int t = blockIdx.x * 256 + threadIdx.x;
    int node = t >> 4;
    if (node >= N) return;
    int c = (t & 15) * 4;

    int s0 = rowptr[node];
    int s1 = rowptr[node + 1];

    float4 acc = *reinterpret_cast<const float4*>(y + (size_t)node * 64 + c);
    float4 b4 = *reinterpret_cast<const float4*>(bias + c);
    acc.x += b4.x; acc.y += b4.y; acc.z += b4.z; acc.w += b4.w;

    for (int j = s0; j < s1; ++j) {
        int s = srcs[j];
        float4 vv = *reinterpret_cast<const float4*>(y + (size_t)s * 64 + c);
        acc.x += vv.x; acc.y += vv.y; acc.z += vv.z; acc.w += vv.w;
    }

    float4 o;
    o.x = fmaxf(acc.x, 0.f);
    o.y = fmaxf(acc.y, 0.f);
    o.z = fmaxf(acc.z, 0.f);
    o.w = fmaxf(acc.w, 0.f);
    *reinterpret_cast<float4*>(zin + (size_t)node * 64 + c) = o;
}

// ---------------- finalize: out[g] = gacc[g]/cnt[g] + fcb ----------------
__global__ __launch_bounds__(256) void finalize_k(
    const float* __restrict__ gacc, const int* __restrict__ batch,
    const float* __restrict__ fcb, float* __restrict__ out, int N, int G)
{
    int g = blockIdx.x * 256 + threadIdx.x;
    if (g >= G) return;
    int lo = 0, hi = N;
    while (lo < hi) { int m = (lo + hi) >> 1; if (batch[m] < g) lo = m + 1; else hi = m; }
    int start = lo;
    hi = N;
    while (lo < hi) { int m = (lo + hi) >> 1; if (batch[m] < g + 1) lo = m + 1; else hi = m; }
    float cnt = fmaxf((float)(lo - start), 1.f);
    out[g] = gacc[g] / cnt + fcb[0];
}

extern "C" void kernel_launch(void* const* d_in, const int* in_sizes, int n_in,
                              void* d_out, int out_size, void* d_ws, size_t ws_size,
                              hipStream_t stream)
{
    const float* x     = (const float*)d_in[0];
    const int*   ei    = (const int*)d_in[1];   // [2, E]
    const int*   batch = (const int*)d_in[2];   // [N], sorted
    const float* W1a   = (const float*)d_in[3];
    const float* b1a   = (const float*)d_in[4];
    const float* W1b   = (const float*)d_in[5];
    const float* b1b   = (const float*)d_in[6];
    const float* W2a   = (const float*)d_in[7];
    const float* b2a   = (const float*)d_in[8];
    const float* W2b   = (const float*)d_in[9];
    const float* b2b   = (const float*)d_in[10];
    const float* fcW   = (const float*)d_in[11];
    const float* fcb   = (const float*)d_in[12];
    float* out = (float*)d_out;

    const int N = NODES, E = EDGES, G = GRAPHS;
    char* ws = (char*)d_ws;
    const size_t szH = (size_t)N * 64 * sizeof(float);   // 51.2 MB

    float* yBuf   = (float*)ws;                 // [0, 51.2)
    float* zinBuf = (float*)(ws + szH);         // [51.2, 102.4)
    float* hBuf   = (float*)(ws + 2 * szH);     // [102.4, 153.6)
    char*  rest   = ws + 3 * szH;
    int* cnt    = (int*)rest;           // N
    int* rowptr = cnt + NODES;          // N+1
    int* cursor = rowptr + NODES + 1;   // N
    int* srcs   = cursor + NODES;       // E
    int* bsum   = srcs + EDGES;         // NB_SCAN
    float* gacc = (float*)(bsum + NB_SCAN + 2);

    // ---- CSR build ----
    hipMemsetAsync(cnt, 0, (size_t)N * sizeof(int), stream);
    hipMemsetAsync(gacc, 0, (size_t)G * sizeof(float), stream);
    count_k<<<NB_SCAN, 256, 0, stream>>>(ei, cnt, E);
    scan1_k<<<NB_SCAN, 256, 0, stream>>>(cnt, rowptr, bsum, N);
    scan2_k<<<1, 1024, 0, stream>>>(bsum, NB_SCAN);
    scan3_k<<<NB_SCAN, 256, 0, stream>>>(rowptr, bsum, cursor, N, E);
    fill_k<<<NB_SCAN, 256, 0, stream>>>(ei, cursor, srcs, E);

    // ---- layer 1 ----
    mm_k<128, false, false><<<N / 64, 256, 0, stream>>>(x, W1a, nullptr, yBuf, N);
    agg_relu_k<<<N * 16 / 256, 256, 0, stream>>>(yBuf, rowptr, srcs, b1a, zinBuf, N);
    mm_k<64, true, true><<<N / 64, 256, 0, stream>>>(zinBuf, W1b, b1b, hBuf, N);

    // ---- layer 2 ----
    mm_k<64, false, false><<<N / 64, 256, 0, stream>>>(hBuf, W2a, nullptr, yBuf, N);
    agg_relu_k<<<N * 16 / 256, 256, 0, stream>>>(yBuf, rowptr, srcs, b2a, zinBuf, N);

    // ---- h2 GEMM fused with pool/fc ----
    mm_pool_k<<<N / 64, 256, 0, stream>>>(zinBuf, W2b, b2b, fcW, batch, gacc, N);
    finalize_k<<<(G + 255) / 256, 256, 0, stream>>>(gacc, batch, fcb, out, N, G);
}

// Round 6
// 328.844 us; speedup vs baseline: 2.3084x; 1.0176x over previous
//
#include <hip/hip_runtime.h>
#include <hip/hip_bf16.h>

// ---------------------------------------------------------------------------
// GIN forward, split-bf16 MFMA everywhere, fragment-precomputed weights:
//   wsplit: W -> hi/lo MFMA fragment arrays in ws (once per call)
//   mm1:    y1 = x @ W1a            (fp32 A, cvt in kernel, 32 rows/wave)
//   agg1:   zin1 = relu(y1 + gather(y1) + b1a) -> split hi/lo bf16 planes
//   mmmm:   h1 = relu(zin1@W1b+b1b); y2 = h1@W2a   (LDS split-transpose)
//   agg2:   zin2 = relu(y2 + gather(y2) + b2a) -> planes
//   mmpool: relu(zin2@W2b+b2b).fcW -> segmented atomicAdd per graph
//   finalize: out[g] = gacc[g]/cnt[g] + fcb
// ---------------------------------------------------------------------------

#define NODES 200000
#define NPAD  200064   // 1563 * 128
#define EDGES 200000
#define GRAPHS 2048
#define NB_SCAN 782    // ceil(NODES/256)

typedef __attribute__((ext_vector_type(8))) short short8;
typedef __attribute__((ext_vector_type(4))) short short4v;
typedef __attribute__((ext_vector_type(4))) float f32x4;

__device__ __forceinline__ unsigned short f2bf(float f) {
    unsigned u = __builtin_bit_cast(unsigned, f);
    u = (u + 0x7fffu + ((u >> 16) & 1u)) >> 16;
    return (unsigned short)u;
}
__device__ __forceinline__ float bf2f(unsigned short h) {
    unsigned u = ((unsigned)h) << 16;
    return __builtin_bit_cast(float, u);
}

// ---------------- CSR build ----------------
__global__ __launch_bounds__(256) void count_k(
    const int* __restrict__ ei, int* __restrict__ cnt, int E)
{
    int e = blockIdx.x * 256 + threadIdx.x;
    if (e < E) atomicAdd(&cnt[ei[E + e]], 1);
}

__global__ __launch_bounds__(256) void scan1_k(
    const int* __restrict__ cnt, int* __restrict__ excl,
    int* __restrict__ bsum, int N)
{
    __shared__ int sh[256];
    int tid = threadIdx.x;
    int i = blockIdx.x * 256 + tid;
    int v = (i < N) ? cnt[i] : 0;
    sh[tid] = v;
    __syncthreads();
    for (int off = 1; off < 256; off <<= 1) {
        int t = (tid >= off) ? sh[tid - off] : 0;
        __syncthreads();
        sh[tid] += t;
        __syncthreads();
    }
    if (i < N) excl[i] = sh[tid] - v;
    if (tid == 255) bsum[blockIdx.x] = sh[255];
}

__global__ __launch_bounds__(1024) void scan2_k(int* __restrict__ bsum, int NB)
{
    __shared__ int sh[1024];
    int tid = threadIdx.x;
    int v = (tid < NB) ? bsum[tid] : 0;
    sh[tid] = v;
    __syncthreads();
    for (int off = 1; off < 1024; off <<= 1) {
        int t = (tid >= off) ? sh[tid - off] : 0;
        __syncthreads();
        sh[tid] += t;
        __syncthreads();
    }
    if (tid < NB) bsum[tid] = sh[tid] - v;
}

__global__ __launch_bounds__(256) void scan3_k(
    int* __restrict__ rowptr, const int* __restrict__ bsum,
    int* __restrict__ cursor, int N, int E)
{
    int i = blockIdx.x * 256 + threadIdx.x;
    if (i < N) {
        int v = rowptr[i] + bsum[blockIdx.x];
        rowptr[i] = v;
        cursor[i] = v;
    }
    if (i == 0) rowptr[N] = E;
}

__global__ __launch_bounds__(256) void fill_k(
    const int* __restrict__ ei, int* __restrict__ cursor,
    int* __restrict__ srcs, int E)
{
    int e = blockIdx.x * 256 + threadIdx.x;
    if (e < E) {
        int d = ei[E + e];
        int p = atomicAdd(&cursor[d], 1);
        srcs[p] = ei[e];
    }
}

// ---------------- weight fragment precompute ----------------
// Fragment array per weight: hi plane [KC][4][64][8] shorts, lo plane after
// (offset NE*8, NE = KC*4*64). element: k = kc*32+(lane>>4)*8+j, col = nb*16+(lane&15)
__device__ __forceinline__ void wconv(const float* __restrict__ W,
                                      short* __restrict__ F, int e, int NE)
{
    int lane = e & 63, nb = (e >> 6) & 3, kc = e >> 8;
    int col = nb * 16 + (lane & 15);
    int kb = kc * 32 + ((lane >> 4) * 8);
    short8 hi, lo;
    #pragma unroll
    for (int j = 0; j < 8; ++j) {
        float w = W[(size_t)(kb + j) * 64 + col];
        unsigned short h = f2bf(w);
        float r = w - bf2f(h);
        hi[j] = (short)h;
        lo[j] = (short)f2bf(r);
    }
    *reinterpret_cast<short8*>(F + (size_t)e * 8) = hi;
    *reinterpret_cast<short8*>(F + (size_t)NE * 8 + (size_t)e * 8) = lo;
}

__global__ __launch_bounds__(256) void wsplit_k(
    const float* __restrict__ W1a, const float* __restrict__ W1b,
    const float* __restrict__ W2a, const float* __restrict__ W2b,
    short* __restrict__ F1a, short* __restrict__ F1b,
    short* __restrict__ F2a, short* __restrict__ F2b)
{
    int t = blockIdx.x * 256 + threadIdx.x;
    if (t < 1024)      wconv(W1a, F1a, t, 1024);
    else if (t < 1536) wconv(W1b, F1b, t - 1024, 512);
    else if (t < 2048) wconv(W2a, F2a, t - 1536, 512);
    else if (t < 2560) wconv(W2b, F2b, t - 2048, 512);
}

// ---------------- mm1: y1 = x @ W1a (K=128, fp32 A) ----------------
__device__ __forceinline__ void cvt_a8(const float4& a, const float4& b,
                                       short8& hi, short8& lo)
{
    float av[8] = {a.x, a.y, a.z, a.w, b.x, b.y, b.z, b.w};
    #pragma unroll
    for (int j = 0; j < 8; ++j) {
        unsigned short h = f2bf(av[j]);
        float r = av[j] - bf2f(h);
        hi[j] = (short)h;
        lo[j] = (short)f2bf(r);
    }
}

__global__ __launch_bounds__(256) void mm1_k(
    const float* __restrict__ A, const short* __restrict__ Wf,
    float* __restrict__ out, int N)
{
    const int tid = threadIdx.x;
    const int lane = tid & 63;
    const int wv = tid >> 6;
    const int row0w = blockIdx.x * 128 + wv * 32;
    const int grp = lane >> 4, c = lane & 15;
    const int koff = grp * 8;

    const float* Ar0 = A + (size_t)min(row0w + c, N - 1) * 128;
    const float* Ar1 = A + (size_t)min(row0w + 16 + c, N - 1) * 128;

    f32x4 acc[2][4];
    #pragma unroll
    for (int rg = 0; rg < 2; ++rg)
        #pragma unroll
        for (int nb = 0; nb < 4; ++nb)
            acc[rg][nb] = (f32x4){0.f, 0.f, 0.f, 0.f};

    #pragma unroll
    for (int kc = 0; kc < 4; ++kc) {
        const int kb = kc * 32 + koff;
        float4 a00 = *reinterpret_cast<const float4*>(Ar0 + kb);
        float4 a01 = *reinterpret_cast<const float4*>(Ar0 + kb + 4);
        float4 a10 = *reinterpret_cast<const float4*>(Ar1 + kb);
        float4 a11 = *reinterpret_cast<const float4*>(Ar1 + kb + 4);
        short8 h0, l0, h1, l1;
        cvt_a8(a00, a01, h0, l0);
        cvt_a8(a10, a11, h1, l1);
        #pragma unroll
        for (int nb = 0; nb < 4; ++nb) {
            short8 whi = *reinterpret_cast<const short8*>(Wf + ((size_t)((kc * 4 + nb) * 64) + lane) * 8);
            short8 wlo = *reinterpret_cast<const short8*>(Wf + ((size_t)(1024 + (kc * 4 + nb) * 64) + lane) * 8);
            acc[0][nb] = __builtin_amdgcn_mfma_f32_16x16x32_bf16(h0, whi, acc[0][nb], 0, 0, 0);
            acc[0][nb] = __builtin_amdgcn_mfma_f32_16x16x32_bf16(l0, whi, acc[0][nb], 0, 0, 0);
            acc[0][nb] = __builtin_amdgcn_mfma_f32_16x16x32_bf16(h0, wlo, acc[0][nb], 0, 0, 0);
            acc[1][nb] = __builtin_amdgcn_mfma_f32_16x16x32_bf16(h1, whi, acc[1][nb], 0, 0, 0);
            acc[1][nb] = __builtin_amdgcn_mfma_f32_16x16x32_bf16(l1, whi, acc[1][nb], 0, 0, 0);
            acc[1][nb] = __builtin_amdgcn_mfma_f32_16x16x32_bf16(h1, wlo, acc[1][nb], 0, 0, 0);
        }
    }

    #pragma unroll
    for (int rg = 0; rg < 2; ++rg)
        #pragma unroll
        for (int nb = 0; nb < 4; ++nb)
            #pragma unroll
            for (int reg = 0; reg < 4; ++reg)
                out[(size_t)(row0w + rg * 16 + grp * 4 + reg) * 64 + nb * 16 + c] = acc[rg][nb][reg];
}

// ---------------- agg: zin = relu(y + gather(y) + b) -> split planes --------
__global__ __launch_bounds__(256) void agg_split_k(
    const float* __restrict__ y, const int* __restrict__ rowptr,
    const int* __restrict__ srcs, const float* __restrict__ bias,
    short* __restrict__ zHi, short* __restrict__ zLo, int N)
{
    int t = blockIdx.x * 256 + threadIdx.x;
    int node = t >> 4;
    if (node >= N) return;
    int c = (t & 15) * 4;

    int s0 = rowptr[node];
    int s1 = rowptr[node + 1];

    float4 acc = *reinterpret_cast<const float4*>(y + (size_t)node * 64 + c);
    float4 b4 = *reinterpret_cast<const float4*>(bias + c);
    acc.x += b4.x; acc.y += b4.y; acc.z += b4.z; acc.w += b4.w;

    for (int j = s0; j < s1; ++j) {
        int s = srcs[j];
        float4 vv = *reinterpret_cast<const float4*>(y + (size_t)s * 64 + c);
        acc.x += vv.x; acc.y += vv.y; acc.z += vv.z; acc.w += vv.w;
    }

    float v[4] = {fmaxf(acc.x, 0.f), fmaxf(acc.y, 0.f),
                  fmaxf(acc.z, 0.f), fmaxf(acc.w, 0.f)};
    short4v hv, lv;
    #pragma unroll
    for (int i = 0; i < 4; ++i) {
        unsigned short h = f2bf(v[i]);
        float r = v[i] - bf2f(h);
        hv[i] = (short)h;
        lv[i] = (short)f2bf(r);
    }
    *reinterpret_cast<short4v*>(zHi + (size_t)node * 64 + c) = hv;
    *reinterpret_cast<short4v*>(zLo + (size_t)node * 64 + c) = lv;
}

// ---------------- K=64 split-plane GEMM core (32 rows/wave) ----------------
__device__ __forceinline__ void mm64_core(
    const short* __restrict__ zHi, const short* __restrict__ zLo,
    const short* __restrict__ Wf, int row0w, int lane, f32x4 acc[2][4])
{
    const int grp = lane >> 4, c = lane & 15;
    const int koff = grp * 8;
    const short* zh0 = zHi + (size_t)(row0w + c) * 64;
    const short* zl0 = zLo + (size_t)(row0w + c) * 64;
    const short* zh1 = zHi + (size_t)(row0w + 16 + c) * 64;
    const short* zl1 = zLo + (size_t)(row0w + 16 + c) * 64;

    #pragma unroll
    for (int kc = 0; kc < 2; ++kc) {
        const int kb = kc * 32 + koff;
        short8 h0 = *reinterpret_cast<const short8*>(zh0 + kb);
        short8 l0 = *reinterpret_cast<const short8*>(zl0 + kb);
        short8 h1 = *reinterpret_cast<const short8*>(zh1 + kb);
        short8 l1 = *reinterpret_cast<const short8*>(zl1 + kb);
        #pragma unroll
        for (int nb = 0; nb < 4; ++nb) {
            short8 whi = *reinterpret_cast<const short8*>(Wf + ((size_t)((kc * 4 + nb) * 64) + lane) * 8);
            short8 wlo = *reinterpret_cast<const short8*>(Wf + ((size_t)(512 + (kc * 4 + nb) * 64) + lane) * 8);
            acc[0][nb] = __builtin_amdgcn_mfma_f32_16x16x32_bf16(h0, whi, acc[0][nb], 0, 0, 0);
            acc[0][nb] = __builtin_amdgcn_mfma_f32_16x16x32_bf16(l0, whi, acc[0][nb], 0, 0, 0);
            acc[0][nb] = __builtin_amdgcn_mfma_f32_16x16x32_bf16(h0, wlo, acc[0][nb], 0, 0, 0);
            acc[1][nb] = __builtin_amdgcn_mfma_f32_16x16x32_bf16(h1, whi, acc[1][nb], 0, 0, 0);
            acc[1][nb] = __builtin_amdgcn_mfma_f32_16x16x32_bf16(l1, whi, acc[1][nb], 0, 0, 0);
            acc[1][nb] = __builtin_amdgcn_mfma_f32_16x16x32_bf16(h1, wlo, acc[1][nb], 0, 0, 0);
        }
    }
}

// ---------------- mmmm: h1 = relu(zin1@W1b+b1b); y2 = h1@W2a ----------------
__global__ __launch_bounds__(256) void mmmm_k(
    const short* __restrict__ zHi, const short* __restrict__ zLo,
    const short* __restrict__ Wf1, const float* __restrict__ b1,
    const short* __restrict__ Wf2, float* __restrict__ out)
{
    __shared__ short hT[4][32 * 72];
    __shared__ short lT[4][32 * 72];
    const int tid = threadIdx.x;
    const int lane = tid & 63;
    const int wv = tid >> 6;
    const int row0w = blockIdx.x * 128 + wv * 32;
    const int grp = lane >> 4, c = lane & 15;
    const int koff = grp * 8;

    f32x4 acc[2][4];
    #pragma unroll
    for (int rg = 0; rg < 2; ++rg)
        #pragma unroll
        for (int nb = 0; nb < 4; ++nb)
            acc[rg][nb] = (f32x4){0.f, 0.f, 0.f, 0.f};

    mm64_core(zHi, zLo, Wf1, row0w, lane, acc);

    // h1 = relu(acc + b1) -> split -> per-wave LDS planes (stride 72 shorts)
    #pragma unroll
    for (int rg = 0; rg < 2; ++rg)
        #pragma unroll
        for (int nb = 0; nb < 4; ++nb) {
            const int col = nb * 16 + c;
            const float bv = b1[col];
            #pragma unroll
            for (int reg = 0; reg < 4; ++reg) {
                const int lr = rg * 16 + grp * 4 + reg;
                float v = fmaxf(acc[rg][nb][reg] + bv, 0.f);
                unsigned short h = f2bf(v);
                float r = v - bf2f(h);
                hT[wv][lr * 72 + col] = (short)h;
                lT[wv][lr * 72 + col] = (short)f2bf(r);
            }
        }
    __syncthreads();

    f32x4 acc2[2][4];
    #pragma unroll
    for (int rg = 0; rg < 2; ++rg)
        #pragma unroll
        for (int nb = 0; nb < 4; ++nb)
            acc2[rg][nb] = (f32x4){0.f, 0.f, 0.f, 0.f};

    #pragma unroll
    for (int kc = 0; kc < 2; ++kc) {
        const int kb = kc * 32 + koff;
        short8 h0 = *reinterpret_cast<const short8*>(&hT[wv][(0 + c) * 72 + kb]);
        short8 l0 = *reinterpret_cast<const short8*>(&lT[wv][(0 + c) * 72 + kb]);
        short8 h1 = *reinterpret_cast<const short8*>(&hT[wv][(16 + c) * 72 + kb]);
        short8 l1 = *reinterpret_cast<const short8*>(&lT[wv][(16 + c) * 72 + kb]);
        #pragma unroll
        for (int nb = 0; nb < 4; ++nb) {
            short8 whi = *reinterpret_cast<const short8*>(Wf2 + ((size_t)((kc * 4 + nb) * 64) + lane) * 8);
            short8 wlo = *reinterpret_cast<const short8*>(Wf2 + ((size_t)(512 + (kc * 4 + nb) * 64) + lane) * 8);
            acc2[0][nb] = __builtin_amdgcn_mfma_f32_16x16x32_bf16(h0, whi, acc2[0][nb], 0, 0, 0);
            acc2[0][nb] = __builtin_amdgcn_mfma_f32_16x16x32_bf16(l0, whi, acc2[0][nb], 0, 0, 0);
            acc2[0][nb] = __builtin_amdgcn_mfma_f32_16x16x32_bf16(h0, wlo, acc2[0][nb], 0, 0, 0);
            acc2[1][nb] = __builtin_amdgcn_mfma_f32_16x16x32_bf16(h1, whi, acc2[1][nb], 0, 0, 0);
            acc2[1][nb] = __builtin_amdgcn_mfma_f32_16x16x32_bf16(l1, whi, acc2[1][nb], 0, 0, 0);
            acc2[1][nb] = __builtin_amdgcn_mfma_f32_16x16x32_bf16(h1, wlo, acc2[1][nb], 0, 0, 0);
        }
    }

    #pragma unroll
    for (int rg = 0; rg < 2; ++rg)
        #pragma unroll
        for (int nb = 0; nb < 4; ++nb)
            #pragma unroll
            for (int reg = 0; reg < 4; ++reg)
                out[(size_t)(row0w + rg * 16 + grp * 4 + reg) * 64 + nb * 16 + c] = acc2[rg][nb][reg];
}

// ---------------- mmpool: relu(zin2@W2b+b2b).fcW -> segmented atomics -------
__global__ __launch_bounds__(256) void mmpool_k(
    const short* __restrict__ zHi, const short* __restrict__ zLo,
    const short* __restrict__ Wf, const float* __restrict__ bias,
    const float* __restrict__ fcW, const int* __restrict__ batch,
    float* __restrict__ gacc, int N)
{
    __shared__ float rd[4][32];
    __shared__ int bls[4][32];
    const int tid = threadIdx.x;
    const int lane = tid & 63;
    const int wv = tid >> 6;
    const int row0w = blockIdx.x * 128 + wv * 32;
    const int grp = lane >> 4, c = lane & 15;

    f32x4 acc[2][4];
    #pragma unroll
    for (int rg = 0; rg < 2; ++rg)
        #pragma unroll
        for (int nb = 0; nb < 4; ++nb)
            acc[rg][nb] = (f32x4){0.f, 0.f, 0.f, 0.f};

    mm64_core(zHi, zLo, Wf, row0w, lane, acc);

    float bv[4], fw[4];
    #pragma unroll
    for (int nb = 0; nb < 4; ++nb) {
        bv[nb] = bias[nb * 16 + c];
        fw[nb] = fcW[nb * 16 + c];
    }
    if (lane < 32) bls[wv][lane] = batch[min(row0w + lane, N - 1)];

    #pragma unroll
    for (int rg = 0; rg < 2; ++rg)
        #pragma unroll
        for (int reg = 0; reg < 4; ++reg) {
            float t = 0.f;
            #pragma unroll
            for (int nb = 0; nb < 4; ++nb)
                t += fmaxf(acc[rg][nb][reg] + bv[nb], 0.f) * fw[nb];
            t += __shfl_xor(t, 1, 16);
            t += __shfl_xor(t, 2, 16);
            t += __shfl_xor(t, 4, 16);
            t += __shfl_xor(t, 8, 16);
            if (c == 0) rd[wv][rg * 16 + grp * 4 + reg] = t;
        }

    if (lane == 0) {
        int cnt = min(32, N - row0w);
        if (cnt > 0) {
            int curg = bls[wv][0];
            float s = rd[wv][0];
            for (int i = 1; i < cnt; ++i) {
                int g = bls[wv][i];
                float v = rd[wv][i];
                if (g == curg) s += v;
                else { atomicAdd(&gacc[curg], s); curg = g; s = v; }
            }
            atomicAdd(&gacc[curg], s);
        }
    }
}

// ---------------- finalize ----------------
__global__ __launch_bounds__(256) void finalize_k(
    const float* __restrict__ gacc, const int* __restrict__ batch,
    const float* __restrict__ fcb, float* __restrict__ out, int N, int G)
{
    int g = blockIdx.x * 256 + threadIdx.x;
    if (g >= G) return;
    int lo = 0, hi = N;
    while (lo < hi) { int m = (lo + hi) >> 1; if (batch[m] < g) lo = m + 1; else hi = m; }
    int start = lo;
    hi = N;
    while (lo < hi) { int m = (lo + hi) >> 1; if (batch[m] < g + 1) lo = m + 1; else hi = m; }
    float cnt = fmaxf((float)(lo - start), 1.f);
    out[g] = gacc[g] / cnt + fcb[0];
}

extern "C" void kernel_launch(void* const* d_in, const int* in_sizes, int n_in,
                              void* d_out, int out_size, void* d_ws, size_t ws_size,
                              hipStream_t stream)
{
    const float* x     = (const float*)d_in[0];
    const int*   ei    = (const int*)d_in[1];
    const int*   batch = (const int*)d_in[2];
    const float* W1a   = (const float*)d_in[3];
    const float* b1a   = (const float*)d_in[4];
    const float* W1b   = (const float*)d_in[5];
    const float* b1b   = (const float*)d_in[6];
    const float* W2a   = (const float*)d_in[7];
    const float* b2a   = (const float*)d_in[8];
    const float* W2b   = (const float*)d_in[9];
    const float* b2b   = (const float*)d_in[10];
    const float* fcW   = (const float*)d_in[11];
    const float* fcb   = (const float*)d_in[12];
    float* out = (float*)d_out;

    const int N = NODES, E = EDGES, G = GRAPHS;
    char* ws = (char*)d_ws;

    float* yBuf = (float*)ws;                                   // NPAD*64 f32
    short* zHi  = (short*)(ws + (size_t)NPAD * 64 * 4);         // NPAD*64 bf16
    short* zLo  = zHi + (size_t)NPAD * 64;                      // NPAD*64 bf16
    char*  rest = (char*)(zLo + (size_t)NPAD * 64);
    int* cnt    = (int*)rest;            // N
    int* rowptr = cnt + NODES;           // N+1
    int* cursor = rowptr + NODES + 1;    // N
    int* srcs   = cursor + NODES;        // E
    int* bsum   = srcs + EDGES;          // NB_SCAN
    float* gacc = (float*)(bsum + NB_SCAN + 2);                 // G
    short* F1a  = (short*)(((size_t)(gacc + GRAPHS) + 63) & ~(size_t)63);
    short* F1b  = F1a + 2 * 1024 * 8;
    short* F2a  = F1b + 2 * 512 * 8;
    short* F2b  = F2a + 2 * 512 * 8;

    const int NBLK = NPAD / 128;   // 1563

    // ---- CSR build + weight fragments ----
    hipMemsetAsync(cnt, 0, (size_t)N * sizeof(int), stream);
    hipMemsetAsync(gacc, 0, (size_t)G * sizeof(float), stream);
    count_k<<<NB_SCAN, 256, 0, stream>>>(ei, cnt, E);
    scan1_k<<<NB_SCAN, 256, 0, stream>>>(cnt, rowptr, bsum, N);
    scan2_k<<<1, 1024, 0, stream>>>(bsum, NB_SCAN);
    scan3_k<<<NB_SCAN, 256, 0, stream>>>(rowptr, bsum, cursor, N, E);
    fill_k<<<NB_SCAN, 256, 0, stream>>>(ei, cursor, srcs, E);
    wsplit_k<<<10, 256, 0, stream>>>(W1a, W1b, W2a, W2b, F1a, F1b, F2a, F2b);

    // ---- layer 1 ----
    mm1_k<<<NBLK, 256, 0, stream>>>(x, F1a, yBuf, N);
    agg_split_k<<<N * 16 / 256, 256, 0, stream>>>(yBuf, rowptr, srcs, b1a, zHi, zLo, N);

    // ---- h1 GEMM + y2 GEMM fused ----
    mmmm_k<<<NBLK, 256, 0, stream>>>(zHi, zLo, F1b, b1b, F2a, yBuf);

    // ---- layer 2 agg ----
    agg_split_k<<<N * 16 / 256, 256, 0, stream>>>(yBuf, rowptr, srcs, b2a, zHi, zLo, N);

    // ---- h2 GEMM fused with pool/fc ----
    mmpool_k<<<NBLK, 256, 0, stream>>>(zHi, zLo, F2b, b2b, fcW, batch, gacc, N);
    finalize_k<<<(G + 255) / 256, 256, 0, stream>>>(gacc, batch, fcb, out, N, G);
}

// Round 7
// 306.403 us; speedup vs baseline: 2.4775x; 1.0732x over previous
//
#include <hip/hip_runtime.h>
#include <hip/hip_bf16.h>

// ---------------------------------------------------------------------------
// GIN forward, split-bf16 MFMA, aggregation FUSED into consuming GEMMs:
//   wsplit: weights -> hi/lo MFMA fragment arrays (once per call)
//   mm1:      y1 = x @ W1a                       (K=128, fp32 A, 32 rows/wave)
//   mmaggmm:  zin1 = relu(y1+gather(y1)+b1a) built per-lane in registers
//             h1 = relu(zin1@W1b+b1b)  (LDS split-transpose)
//             y2 = h1@W2a
//   mmaggpool: zin2 = relu(y2+gather(y2)+b2a) in registers
//             relu(zin2@W2b+b2b).fcW -> segmented atomicAdd per graph
//   finalize: out[g] = gacc[g]/cnt[g] + fcb
// ---------------------------------------------------------------------------

#define NODES 200000
#define NPAD  200064   // 1563 * 128
#define EDGES 200000
#define GRAPHS 2048
#define NB_SCAN 782    // ceil(NODES/256)

typedef __attribute__((ext_vector_type(8))) short short8;
typedef __attribute__((ext_vector_type(4))) float f32x4;

__device__ __forceinline__ unsigned short f2bf(float f) {
    unsigned u = __builtin_bit_cast(unsigned, f);
    u = (u + 0x7fffu + ((u >> 16) & 1u)) >> 16;
    return (unsigned short)u;
}
__device__ __forceinline__ float bf2f(unsigned short h) {
    unsigned u = ((unsigned)h) << 16;
    return __builtin_bit_cast(float, u);
}

// ---------------- CSR build ----------------
__global__ __launch_bounds__(256) void count_k(
    const int* __restrict__ ei, int* __restrict__ cnt, int E)
{
    int e = blockIdx.x * 256 + threadIdx.x;
    if (e < E) atomicAdd(&cnt[ei[E + e]], 1);
}

__global__ __launch_bounds__(256) void scan1_k(
    const int* __restrict__ cnt, int* __restrict__ excl,
    int* __restrict__ bsum, int N)
{
    __shared__ int sh[256];
    int tid = threadIdx.x;
    int i = blockIdx.x * 256 + tid;
    int v = (i < N) ? cnt[i] : 0;
    sh[tid] = v;
    __syncthreads();
    for (int off = 1; off < 256; off <<= 1) {
        int t = (tid >= off) ? sh[tid - off] : 0;
        __syncthreads();
        sh[tid] += t;
        __syncthreads();
    }
    if (i < N) excl[i] = sh[tid] - v;
    if (tid == 255) bsum[blockIdx.x] = sh[255];
}

__global__ __launch_bounds__(1024) void scan2_k(int* __restrict__ bsum, int NB)
{
    __shared__ int sh[1024];
    int tid = threadIdx.x;
    int v = (tid < NB) ? bsum[tid] : 0;
    sh[tid] = v;
    __syncthreads();
    for (int off = 1; off < 1024; off <<= 1) {
        int t = (tid >= off) ? sh[tid - off] : 0;
        __syncthreads();
        sh[tid] += t;
        __syncthreads();
    }
    if (tid < NB) bsum[tid] = sh[tid] - v;
}

__global__ __launch_bounds__(256) void scan3_k(
    int* __restrict__ rowptr, const int* __restrict__ bsum,
    int* __restrict__ cursor, int N, int E)
{
    int i = blockIdx.x * 256 + threadIdx.x;
    if (i < N) {
        int v = rowptr[i] + bsum[blockIdx.x];
        rowptr[i] = v;
        cursor[i] = v;
    }
    if (i == 0) rowptr[N] = E;
}

__global__ __launch_bounds__(256) void fill_k(
    const int* __restrict__ ei, int* __restrict__ cursor,
    int* __restrict__ srcs, int E)
{
    int e = blockIdx.x * 256 + threadIdx.x;
    if (e < E) {
        int d = ei[E + e];
        int p = atomicAdd(&cursor[d], 1);
        srcs[p] = ei[e];
    }
}

// ---------------- weight fragment precompute ----------------
// hi plane: [KC][4][64][8] shorts; lo plane at +NE*8 (NE = KC*4*64)
// element: k = kc*32+(lane>>4)*8+j, col = nb*16+(lane&15)
__device__ __forceinline__ void wconv(const float* __restrict__ W,
                                      short* __restrict__ F, int e, int NE)
{
    int lane = e & 63, nb = (e >> 6) & 3, kc = e >> 8;
    int col = nb * 16 + (lane & 15);
    int kb = kc * 32 + ((lane >> 4) * 8);
    short8 hi, lo;
    #pragma unroll
    for (int j = 0; j < 8; ++j) {
        float w = W[(size_t)(kb + j) * 64 + col];
        unsigned short h = f2bf(w);
        float r = w - bf2f(h);
        hi[j] = (short)h;
        lo[j] = (short)f2bf(r);
    }
    *reinterpret_cast<short8*>(F + (size_t)e * 8) = hi;
    *reinterpret_cast<short8*>(F + (size_t)NE * 8 + (size_t)e * 8) = lo;
}

__global__ __launch_bounds__(256) void wsplit_k(
    const float* __restrict__ W1a, const float* __restrict__ W1b,
    const float* __restrict__ W2a, const float* __restrict__ W2b,
    short* __restrict__ F1a, short* __restrict__ F1b,
    short* __restrict__ F2a, short* __restrict__ F2b)
{
    int t = blockIdx.x * 256 + threadIdx.x;
    if (t < 1024)      wconv(W1a, F1a, t, 1024);
    else if (t < 1536) wconv(W1b, F1b, t - 1024, 512);
    else if (t < 2048) wconv(W2a, F2a, t - 1536, 512);
    else if (t < 2560) wconv(W2b, F2b, t - 2048, 512);
}

// ---------------- mm1: y1 = x @ W1a (K=128, fp32 A) ----------------
__device__ __forceinline__ void cvt_a8(const float4& a, const float4& b,
                                       short8& hi, short8& lo)
{
    float av[8] = {a.x, a.y, a.z, a.w, b.x, b.y, b.z, b.w};
    #pragma unroll
    for (int j = 0; j < 8; ++j) {
        unsigned short h = f2bf(av[j]);
        float r = av[j] - bf2f(h);
        hi[j] = (short)h;
        lo[j] = (short)f2bf(r);
    }
}

__global__ __launch_bounds__(256) void mm1_k(
    const float* __restrict__ A, const short* __restrict__ Wf,
    float* __restrict__ out, int N)
{
    const int tid = threadIdx.x;
    const int lane = tid & 63;
    const int wv = tid >> 6;
    const int row0w = blockIdx.x * 128 + wv * 32;
    const int grp = lane >> 4, c = lane & 15;
    const int koff = grp * 8;

    const float* Ar0 = A + (size_t)min(row0w + c, N - 1) * 128;
    const float* Ar1 = A + (size_t)min(row0w + 16 + c, N - 1) * 128;

    f32x4 acc[2][4];
    #pragma unroll
    for (int rg = 0; rg < 2; ++rg)
        #pragma unroll
        for (int nb = 0; nb < 4; ++nb)
            acc[rg][nb] = (f32x4){0.f, 0.f, 0.f, 0.f};

    #pragma unroll
    for (int kc = 0; kc < 4; ++kc) {
        const int kb = kc * 32 + koff;
        float4 a00 = *reinterpret_cast<const float4*>(Ar0 + kb);
        float4 a01 = *reinterpret_cast<const float4*>(Ar0 + kb + 4);
        float4 a10 = *reinterpret_cast<const float4*>(Ar1 + kb);
        float4 a11 = *reinterpret_cast<const float4*>(Ar1 + kb + 4);
        short8 h0, l0, h1, l1;
        cvt_a8(a00, a01, h0, l0);
        cvt_a8(a10, a11, h1, l1);
        #pragma unroll
        for (int nb = 0; nb < 4; ++nb) {
            short8 whi = *reinterpret_cast<const short8*>(Wf + ((size_t)((kc * 4 + nb) * 64) + lane) * 8);
            short8 wlo = *reinterpret_cast<const short8*>(Wf + ((size_t)(1024 + (kc * 4 + nb) * 64) + lane) * 8);
            acc[0][nb] = __builtin_amdgcn_mfma_f32_16x16x32_bf16(h0, whi, acc[0][nb], 0, 0, 0);
            acc[0][nb] = __builtin_amdgcn_mfma_f32_16x16x32_bf16(l0, whi, acc[0][nb], 0, 0, 0);
            acc[0][nb] = __builtin_amdgcn_mfma_f32_16x16x32_bf16(h0, wlo, acc[0][nb], 0, 0, 0);
            acc[1][nb] = __builtin_amdgcn_mfma_f32_16x16x32_bf16(h1, whi, acc[1][nb], 0, 0, 0);
            acc[1][nb] = __builtin_amdgcn_mfma_f32_16x16x32_bf16(l1, whi, acc[1][nb], 0, 0, 0);
            acc[1][nb] = __builtin_amdgcn_mfma_f32_16x16x32_bf16(h1, wlo, acc[1][nb], 0, 0, 0);
        }
    }

    #pragma unroll
    for (int rg = 0; rg < 2; ++rg)
        #pragma unroll
        for (int nb = 0; nb < 4; ++nb)
            #pragma unroll
            for (int reg = 0; reg < 4; ++reg)
                out[(size_t)(row0w + rg * 16 + grp * 4 + reg) * 64 + nb * 16 + c] = acc[rg][nb][reg];
}

// ---------------- fused agg -> A fragments (per-lane, in registers) ---------
// Builds zin[n] slices (cols koff..koff+8 and 32+koff..+8) where
// zin = relu(y[n] + sum_{s in adj(n)} y[s] + bias); splits into hi/lo bf16.
// fh/fl[kc] is the MFMA A-fragment for k-chunk kc.
__device__ __forceinline__ void agg_frag16(
    const float* __restrict__ y, const int* __restrict__ rowptr,
    const int* __restrict__ srcs, const float* __restrict__ bias,
    int n, int koff, bool valid, short8 fh[2], short8 fl[2])
{
    if (!valid) {
        #pragma unroll
        for (int i = 0; i < 8; ++i) {
            fh[0][i] = 0; fl[0][i] = 0; fh[1][i] = 0; fl[1][i] = 0;
        }
        return;
    }
    float a[16];
    {
        const float* yr = y + (size_t)n * 64;
        float4 a0 = *reinterpret_cast<const float4*>(yr + koff);
        float4 a1 = *reinterpret_cast<const float4*>(yr + koff + 4);
        float4 a2 = *reinterpret_cast<const float4*>(yr + 32 + koff);
        float4 a3 = *reinterpret_cast<const float4*>(yr + 32 + koff + 4);
        float4 b0 = *reinterpret_cast<const float4*>(bias + koff);
        float4 b1 = *reinterpret_cast<const float4*>(bias + koff + 4);
        float4 b2 = *reinterpret_cast<const float4*>(bias + 32 + koff);
        float4 b3 = *reinterpret_cast<const float4*>(bias + 32 + koff + 4);
        a[0] = a0.x + b0.x;  a[1] = a0.y + b0.y;  a[2] = a0.z + b0.z;  a[3] = a0.w + b0.w;
        a[4] = a1.x + b1.x;  a[5] = a1.y + b1.y;  a[6] = a1.z + b1.z;  a[7] = a1.w + b1.w;
        a[8] = a2.x + b2.x;  a[9] = a2.y + b2.y;  a[10] = a2.z + b2.z; a[11] = a2.w + b2.w;
        a[12] = a3.x + b3.x; a[13] = a3.y + b3.y; a[14] = a3.z + b3.z; a[15] = a3.w + b3.w;
    }
    int s0 = rowptr[n], s1 = rowptr[n + 1];
    for (int j = s0; j < s1; ++j) {
        const float* ys = y + (size_t)srcs[j] * 64;
        float4 v0 = *reinterpret_cast<const float4*>(ys + koff);
        float4 v1 = *reinterpret_cast<const float4*>(ys + koff + 4);
        float4 v2 = *reinterpret_cast<const float4*>(ys + 32 + koff);
        float4 v3 = *reinterpret_cast<const float4*>(ys + 32 + koff + 4);
        a[0] += v0.x;  a[1] += v0.y;  a[2] += v0.z;  a[3] += v0.w;
        a[4] += v1.x;  a[5] += v1.y;  a[6] += v1.z;  a[7] += v1.w;
        a[8] += v2.x;  a[9] += v2.y;  a[10] += v2.z; a[11] += v2.w;
        a[12] += v3.x; a[13] += v3.y; a[14] += v3.z; a[15] += v3.w;
    }
    #pragma unroll
    for (int i = 0; i < 16; ++i) {
        float v = fmaxf(a[i], 0.f);
        unsigned short h = f2bf(v);
        float r = v - bf2f(h);
        fh[i >> 3][i & 7] = (short)h;
        fl[i >> 3][i & 7] = (short)f2bf(r);
    }
}

// ---------------- mmaggmm: y2 = relu(agg(y1)@W1b+b1b)@W2a ----------------
__global__ __launch_bounds__(256) void mmaggmm_k(
    const float* __restrict__ y, const int* __restrict__ rowptr,
    const int* __restrict__ srcs, const float* __restrict__ bagg,
    const short* __restrict__ Wf1, const float* __restrict__ b1,
    const short* __restrict__ Wf2, float* __restrict__ out, int N)
{
    __shared__ short hT[4][32 * 72];
    __shared__ short lT[4][32 * 72];
    const int tid = threadIdx.x;
    const int lane = tid & 63;
    const int wv = tid >> 6;
    const int row0w = blockIdx.x * 128 + wv * 32;
    const int grp = lane >> 4, c = lane & 15;
    const int koff = grp * 8;

    short8 fh0[2], fl0[2], fh1[2], fl1[2];
    {
        int n0 = row0w + c;
        int n1 = row0w + 16 + c;
        agg_frag16(y, rowptr, srcs, bagg, n0, koff, n0 < N, fh0, fl0);
        agg_frag16(y, rowptr, srcs, bagg, n1, koff, n1 < N, fh1, fl1);
    }

    f32x4 acc[2][4];
    #pragma unroll
    for (int rg = 0; rg < 2; ++rg)
        #pragma unroll
        for (int nb = 0; nb < 4; ++nb)
            acc[rg][nb] = (f32x4){0.f, 0.f, 0.f, 0.f};

    #pragma unroll
    for (int kc = 0; kc < 2; ++kc) {
        #pragma unroll
        for (int nb = 0; nb < 4; ++nb) {
            short8 whi = *reinterpret_cast<const short8*>(Wf1 + ((size_t)((kc * 4 + nb) * 64) + lane) * 8);
            short8 wlo = *reinterpret_cast<const short8*>(Wf1 + ((size_t)(512 + (kc * 4 + nb) * 64) + lane) * 8);
            acc[0][nb] = __builtin_amdgcn_mfma_f32_16x16x32_bf16(fh0[kc], whi, acc[0][nb], 0, 0, 0);
            acc[0][nb] = __builtin_amdgcn_mfma_f32_16x16x32_bf16(fl0[kc], whi, acc[0][nb], 0, 0, 0);
            acc[0][nb] = __builtin_amdgcn_mfma_f32_16x16x32_bf16(fh0[kc], wlo, acc[0][nb], 0, 0, 0);
            acc[1][nb] = __builtin_amdgcn_mfma_f32_16x16x32_bf16(fh1[kc], whi, acc[1][nb], 0, 0, 0);
            acc[1][nb] = __builtin_amdgcn_mfma_f32_16x16x32_bf16(fl1[kc], whi, acc[1][nb], 0, 0, 0);
            acc[1][nb] = __builtin_amdgcn_mfma_f32_16x16x32_bf16(fh1[kc], wlo, acc[1][nb], 0, 0, 0);
        }
    }

    // h1 = relu(acc + b1) -> split -> per-wave LDS planes (stride 72 shorts)
    #pragma unroll
    for (int rg = 0; rg < 2; ++rg)
        #pragma unroll
        for (int nb = 0; nb < 4; ++nb) {
            const int col = nb * 16 + c;
            const float bv = b1[col];
            #pragma unroll
            for (int reg = 0; reg < 4; ++reg) {
                const int lr = rg * 16 + grp * 4 + reg;
                float v = fmaxf(acc[rg][nb][reg] + bv, 0.f);
                unsigned short h = f2bf(v);
                float r = v - bf2f(h);
                hT[wv][lr * 72 + col] = (short)h;
                lT[wv][lr * 72 + col] = (short)f2bf(r);
            }
        }
    __syncthreads();

    f32x4 acc2[2][4];
    #pragma unroll
    for (int rg = 0; rg < 2; ++rg)
        #pragma unroll
        for (int nb = 0; nb < 4; ++nb)
            acc2[rg][nb] = (f32x4){0.f, 0.f, 0.f, 0.f};

    #pragma unroll
    for (int kc = 0; kc < 2; ++kc) {
        const int kb = kc * 32 + koff;
        short8 h0 = *reinterpret_cast<const short8*>(&hT[wv][(0 + c) * 72 + kb]);
        short8 l0 = *reinterpret_cast<const short8*>(&lT[wv][(0 + c) * 72 + kb]);
        short8 h1 = *reinterpret_cast<const short8*>(&hT[wv][(16 + c) * 72 + kb]);
        short8 l1 = *reinterpret_cast<const short8*>(&lT[wv][(16 + c) * 72 + kb]);
        #pragma unroll
        for (int nb = 0; nb < 4; ++nb) {
            short8 whi = *reinterpret_cast<const short8*>(Wf2 + ((size_t)((kc * 4 + nb) * 64) + lane) * 8);
            short8 wlo = *reinterpret_cast<const short8*>(Wf2 + ((size_t)(512 + (kc * 4 + nb) * 64) + lane) * 8);
            acc2[0][nb] = __builtin_amdgcn_mfma_f32_16x16x32_bf16(h0, whi, acc2[0][nb], 0, 0, 0);
            acc2[0][nb] = __builtin_amdgcn_mfma_f32_16x16x32_bf16(l0, whi, acc2[0][nb], 0, 0, 0);
            acc2[0][nb] = __builtin_amdgcn_mfma_f32_16x16x32_bf16(h0, wlo, acc2[0][nb], 0, 0, 0);
            acc2[1][nb] = __builtin_amdgcn_mfma_f32_16x16x32_bf16(h1, whi, acc2[1][nb], 0, 0, 0);
            acc2[1][nb] = __builtin_amdgcn_mfma_f32_16x16x32_bf16(l1, whi, acc2[1][nb], 0, 0, 0);
            acc2[1][nb] = __builtin_amdgcn_mfma_f32_16x16x32_bf16(h1, wlo, acc2[1][nb], 0, 0, 0);
        }
    }

    #pragma unroll
    for (int rg = 0; rg < 2; ++rg)
        #pragma unroll
        for (int nb = 0; nb < 4; ++nb)
            #pragma unroll
            for (int reg = 0; reg < 4; ++reg)
                out[(size_t)(row0w + rg * 16 + grp * 4 + reg) * 64 + nb * 16 + c] = acc2[rg][nb][reg];
}

// ---------------- mmaggpool: relu(agg(y2)@W2b+b2b).fcW -> atomics ----------
__global__ __launch_bounds__(256) void mmaggpool_k(
    const float* __restrict__ y, const int* __restrict__ rowptr,
    const int* __restrict__ srcs, const float* __restrict__ bagg,
    const short* __restrict__ Wf, const float* __restrict__ bias,
    const float* __restrict__ fcW, const int* __restrict__ batch,
    float* __restrict__ gacc, int N)
{
    __shared__ float rd[4][32];
    __shared__ int bls[4][32];
    const int tid = threadIdx.x;
    const int lane = tid & 63;
    const int wv = tid >> 6;
    const int row0w = blockIdx.x * 128 + wv * 32;
    const int grp = lane >> 4, c = lane & 15;
    const int koff = grp * 8;

    short8 fh0[2], fl0[2], fh1[2], fl1[2];
    {
        int n0 = row0w + c;
        int n1 = row0w + 16 + c;
        agg_frag16(y, rowptr, srcs, bagg, n0, koff, n0 < N, fh0, fl0);
        agg_frag16(y, rowptr, srcs, bagg, n1, koff, n1 < N, fh1, fl1);
    }

    f32x4 acc[2][4];
    #pragma unroll
    for (int rg = 0; rg < 2; ++rg)
        #pragma unroll
        for (int nb = 0; nb < 4; ++nb)
            acc[rg][nb] = (f32x4){0.f, 0.f, 0.f, 0.f};

    #pragma unroll
    for (int kc = 0; kc < 2; ++kc) {
        #pragma unroll
        for (int nb = 0; nb < 4; ++nb) {
            short8 whi = *reinterpret_cast<const short8*>(Wf + ((size_t)((kc * 4 + nb) * 64) + lane) * 8);
            short8 wlo = *reinterpret_cast<const short8*>(Wf + ((size_t)(512 + (kc * 4 + nb) * 64) + lane) * 8);
            acc[0][nb] = __builtin_amdgcn_mfma_f32_16x16x32_bf16(fh0[kc], whi, acc[0][nb], 0, 0, 0);
            acc[0][nb] = __builtin_amdgcn_mfma_f32_16x16x32_bf16(fl0[kc], whi, acc[0][nb], 0, 0, 0);
            acc[0][nb] = __builtin_amdgcn_mfma_f32_16x16x32_bf16(fh0[kc], wlo, acc[0][nb], 0, 0, 0);
            acc[1][nb] = __builtin_amdgcn_mfma_f32_16x16x32_bf16(fh1[kc], whi, acc[1][nb], 0, 0, 0);
            acc[1][nb] = __builtin_amdgcn_mfma_f32_16x16x32_bf16(fl1[kc], whi, acc[1][nb], 0, 0, 0);
            acc[1][nb] = __builtin_amdgcn_mfma_f32_16x16x32_bf16(fh1[kc], wlo, acc[1][nb], 0, 0, 0);
        }
    }

    float bv[4], fw[4];
    #pragma unroll
    for (int nb = 0; nb < 4; ++nb) {
        bv[nb] = bias[nb * 16 + c];
        fw[nb] = fcW[nb * 16 + c];
    }
    if (lane < 32) bls[wv][lane] = batch[min(row0w + lane, N - 1)];

    #pragma unroll
    for (int rg = 0; rg < 2; ++rg)
        #pragma unroll
        for (int reg = 0; reg < 4; ++reg) {
            float t = 0.f;
            #pragma unroll
            for (int nb = 0; nb < 4; ++nb)
                t += fmaxf(acc[rg][nb][reg] + bv[nb], 0.f) * fw[nb];
            t += __shfl_xor(t, 1, 16);
            t += __shfl_xor(t, 2, 16);
            t += __shfl_xor(t, 4, 16);
            t += __shfl_xor(t, 8, 16);
            if (c == 0) rd[wv][rg * 16 + grp * 4 + reg] = t;
        }

    if (lane == 0) {
        int cnt = min(32, N - row0w);
        if (cnt > 0) {
            int curg = bls[wv][0];
            float s = rd[wv][0];
            for (int i = 1; i < cnt; ++i) {
                int g = bls[wv][i];
                float v = rd[wv][i];
                if (g == curg) s += v;
                else { atomicAdd(&gacc[curg], s); curg = g; s = v; }
            }
            atomicAdd(&gacc[curg], s);
        }
    }
}

// ---------------- finalize ----------------
__global__ __launch_bounds__(256) void finalize_k(
    const float* __restrict__ gacc, const int* __restrict__ batch,
    const float* __restrict__ fcb, float* __restrict__ out, int N, int G)
{
    int g = blockIdx.x * 256 + threadIdx.x;
    if (g >= G) return;
    int lo = 0, hi = N;
    while (lo < hi) { int m = (lo + hi) >> 1; if (batch[m] < g) lo = m + 1; else hi = m; }
    int start = lo;
    hi = N;
    while (lo < hi) { int m = (lo + hi) >> 1; if (batch[m] < g + 1) lo = m + 1; else hi = m; }
    float cnt = fmaxf((float)(lo - start), 1.f);
    out[g] = gacc[g] / cnt + fcb[0];
}

extern "C" void kernel_launch(void* const* d_in, const int* in_sizes, int n_in,
                              void* d_out, int out_size, void* d_ws, size_t ws_size,
                              hipStream_t stream)
{
    const float* x     = (const float*)d_in[0];
    const int*   ei    = (const int*)d_in[1];
    const int*   batch = (const int*)d_in[2];
    const float* W1a   = (const float*)d_in[3];
    const float* b1a   = (const float*)d_in[4];
    const float* W1b   = (const float*)d_in[5];
    const float* b1b   = (const float*)d_in[6];
    const float* W2a   = (const float*)d_in[7];
    const float* b2a   = (const float*)d_in[8];
    const float* W2b   = (const float*)d_in[9];
    const float* b2b   = (const float*)d_in[10];
    const float* fcW   = (const float*)d_in[11];
    const float* fcb   = (const float*)d_in[12];
    float* out = (float*)d_out;

    const int N = NODES, E = EDGES, G = GRAPHS;
    char* ws = (char*)d_ws;

    float* y1 = (float*)ws;                                    // NPAD*64 f32
    float* y2 = (float*)(ws + (size_t)NPAD * 64 * 4);          // NPAD*64 f32
    char*  rest = ws + 2 * (size_t)NPAD * 64 * 4;
    int* cnt    = (int*)rest;            // N
    int* rowptr = cnt + NODES;           // N+1
    int* cursor = rowptr + NODES + 1;    // N
    int* srcs   = cursor + NODES;        // E
    int* bsum   = srcs + EDGES;          // NB_SCAN
    float* gacc = (float*)(bsum + NB_SCAN + 2);                // G
    short* F1a  = (short*)(((size_t)(gacc + GRAPHS) + 63) & ~(size_t)63);
    short* F1b  = F1a + 2 * 1024 * 8;
    short* F2a  = F1b + 2 * 512 * 8;
    short* F2b  = F2a + 2 * 512 * 8;

    const int NBLK = NPAD / 128;   // 1563

    // ---- CSR build + weight fragments ----
    hipMemsetAsync(cnt, 0, (size_t)N * sizeof(int), stream);
    hipMemsetAsync(gacc, 0, (size_t)G * sizeof(float), stream);
    count_k<<<NB_SCAN, 256, 0, stream>>>(ei, cnt, E);
    scan1_k<<<NB_SCAN, 256, 0, stream>>>(cnt, rowptr, bsum, N);
    scan2_k<<<1, 1024, 0, stream>>>(bsum, NB_SCAN);
    scan3_k<<<NB_SCAN, 256, 0, stream>>>(rowptr, bsum, cursor, N, E);
    fill_k<<<NB_SCAN, 256, 0, stream>>>(ei, cursor, srcs, E);
    wsplit_k<<<10, 256, 0, stream>>>(W1a, W1b, W2a, W2b, F1a, F1b, F2a, F2b);

    // ---- layer 1 GEMM ----
    mm1_k<<<NBLK, 256, 0, stream>>>(x, F1a, y1, N);

    // ---- agg1 + h1-GEMM + y2-GEMM (fused) ----
    mmaggmm_k<<<NBLK, 256, 0, stream>>>(y1, rowptr, srcs, b1a, F1b, b1b, F2a, y2, N);

    // ---- agg2 + h2-GEMM + pool (fused) ----
    mmaggpool_k<<<NBLK, 256, 0, stream>>>(y2, rowptr, srcs, b2a, F2b, b2b, fcW, batch, gacc, N);
    finalize_k<<<(G + 255) / 256, 256, 0, stream>>>(gacc, batch, fcb, out, N, G);
}

// Round 8
// 290.691 us; speedup vs baseline: 2.6114x; 1.0540x over previous
//
#include <hip/hip_runtime.h>
#include <hip/hip_bf16.h>

// ---------------------------------------------------------------------------
// GIN forward, split-bf16 MFMA, fused aggregation, compressed dispatch chain:
//   setup_k:  zero cnt/gacc + weight hi/lo fragment precompute   (1 kernel)
//   count_k:  in-degree histogram
//   scan1_k:  per-block exclusive scan
//   scan23_k: block-offset reduce + rowptr/cursor finalize
//   fill_k:   CSR adjacency fill
//   mm1_k:    y1 = x @ W1a                      (K=128, 32 rows/wave)
//   mmaggmm_k: zin1=relu(y1+gather+b1a) in regs; h1=relu(zin1@W1b+b1b) (LDS);
//              y2 = h1@W2a
//   mmaggpool_k: zin2=relu(y2+gather+b2a); relu(zin2@W2b+b2b).fcW ->
//              segmented atomicAdd per graph
//   finalize_k: out[g] = gacc[g]/cnt[g] + fcb
// 9 dispatches total (was 14).
// ---------------------------------------------------------------------------

#define NODES 200000
#define NPAD  200064   // 1563 * 128
#define EDGES 200000
#define GRAPHS 2048
#define NB_SCAN 782    // ceil(NODES/256)

typedef __attribute__((ext_vector_type(8))) short short8;
typedef __attribute__((ext_vector_type(4))) float f32x4;

__device__ __forceinline__ unsigned short f2bf(float f) {
    unsigned u = __builtin_bit_cast(unsigned, f);
    u = (u + 0x7fffu + ((u >> 16) & 1u)) >> 16;
    return (unsigned short)u;
}
__device__ __forceinline__ float bf2f(unsigned short h) {
    unsigned u = ((unsigned)h) << 16;
    return __builtin_bit_cast(float, u);
}

// ---------------- weight fragment precompute ----------------
// hi plane: [KC][4][64][8] shorts; lo plane at +NE*8 (NE = KC*4*64)
// element: k = kc*32+(lane>>4)*8+j, col = nb*16+(lane&15)
__device__ __forceinline__ void wconv(const float* __restrict__ W,
                                      short* __restrict__ F, int e, int NE)
{
    int lane = e & 63, nb = (e >> 6) & 3, kc = e >> 8;
    int col = nb * 16 + (lane & 15);
    int kb = kc * 32 + ((lane >> 4) * 8);
    short8 hi, lo;
    #pragma unroll
    for (int j = 0; j < 8; ++j) {
        float w = W[(size_t)(kb + j) * 64 + col];
        unsigned short h = f2bf(w);
        float r = w - bf2f(h);
        hi[j] = (short)h;
        lo[j] = (short)f2bf(r);
    }
    *reinterpret_cast<short8*>(F + (size_t)e * 8) = hi;
    *reinterpret_cast<short8*>(F + (size_t)NE * 8 + (size_t)e * 8) = lo;
}

// ---------------- setup: zero cnt/gacc + wsplit ----------------
__global__ __launch_bounds__(256) void setup_k(
    const float* __restrict__ W1a, const float* __restrict__ W1b,
    const float* __restrict__ W2a, const float* __restrict__ W2b,
    short* __restrict__ F1a, short* __restrict__ F1b,
    short* __restrict__ F2a, short* __restrict__ F2b,
    int* __restrict__ cnt, float* __restrict__ gacc)
{
    int t = blockIdx.x * 256 + threadIdx.x;
    if (t < NODES) cnt[t] = 0;
    if (t < GRAPHS) gacc[t] = 0.f;
    if (t < 1024)      wconv(W1a, F1a, t, 1024);
    else if (t < 1536) wconv(W1b, F1b, t - 1024, 512);
    else if (t < 2048) wconv(W2a, F2a, t - 1536, 512);
    else if (t < 2560) wconv(W2b, F2b, t - 2048, 512);
}

// ---------------- CSR build ----------------
__global__ __launch_bounds__(256) void count_k(
    const int* __restrict__ ei, int* __restrict__ cnt, int E)
{
    int e = blockIdx.x * 256 + threadIdx.x;
    if (e < E) atomicAdd(&cnt[ei[E + e]], 1);
}

__global__ __launch_bounds__(256) void scan1_k(
    const int* __restrict__ cnt, int* __restrict__ excl,
    int* __restrict__ bsum, int N)
{
    __shared__ int sh[256];
    int tid = threadIdx.x;
    int i = blockIdx.x * 256 + tid;
    int v = (i < N) ? cnt[i] : 0;
    sh[tid] = v;
    __syncthreads();
    for (int off = 1; off < 256; off <<= 1) {
        int t = (tid >= off) ? sh[tid - off] : 0;
        __syncthreads();
        sh[tid] += t;
        __syncthreads();
    }
    if (i < N) excl[i] = sh[tid] - v;
    if (tid == 255) bsum[blockIdx.x] = sh[255];
}

// per-block: offset = sum(bsum[0..blockIdx)); rowptr += offset; cursor = rowptr
__global__ __launch_bounds__(256) void scan23_k(
    int* __restrict__ rowptr, const int* __restrict__ bsum,
    int* __restrict__ cursor, int N, int E)
{
    __shared__ int wsum[4];
    __shared__ int soff;
    int tid = threadIdx.x;
    int partial = 0;
    for (int b = tid; b < blockIdx.x; b += 256) partial += bsum[b];
    #pragma unroll
    for (int off = 32; off >= 1; off >>= 1) partial += __shfl_down(partial, off);
    if ((tid & 63) == 0) wsum[tid >> 6] = partial;
    __syncthreads();
    if (tid == 0) soff = wsum[0] + wsum[1] + wsum[2] + wsum[3];
    __syncthreads();
    int i = blockIdx.x * 256 + tid;
    if (i < N) {
        int v = rowptr[i] + soff;
        rowptr[i] = v;
        cursor[i] = v;
    }
    if (i == 0) rowptr[N] = E;
}

__global__ __launch_bounds__(256) void fill_k(
    const int* __restrict__ ei, int* __restrict__ cursor,
    int* __restrict__ srcs, int E)
{
    int e = blockIdx.x * 256 + threadIdx.x;
    if (e < E) {
        int d = ei[E + e];
        int p = atomicAdd(&cursor[d], 1);
        srcs[p] = ei[e];
    }
}

// ---------------- mm1: y1 = x @ W1a (K=128, fp32 A) ----------------
__device__ __forceinline__ void cvt_a8(const float4& a, const float4& b,
                                       short8& hi, short8& lo)
{
    float av[8] = {a.x, a.y, a.z, a.w, b.x, b.y, b.z, b.w};
    #pragma unroll
    for (int j = 0; j < 8; ++j) {
        unsigned short h = f2bf(av[j]);
        float r = av[j] - bf2f(h);
        hi[j] = (short)h;
        lo[j] = (short)f2bf(r);
    }
}

__global__ __launch_bounds__(256) void mm1_k(
    const float* __restrict__ A, const short* __restrict__ Wf,
    float* __restrict__ out, int N)
{
    const int tid = threadIdx.x;
    const int lane = tid & 63;
    const int wv = tid >> 6;
    const int row0w = blockIdx.x * 128 + wv * 32;
    const int grp = lane >> 4, c = lane & 15;
    const int koff = grp * 8;

    const float* Ar0 = A + (size_t)min(row0w + c, N - 1) * 128;
    const float* Ar1 = A + (size_t)min(row0w + 16 + c, N - 1) * 128;

    f32x4 acc[2][4];
    #pragma unroll
    for (int rg = 0; rg < 2; ++rg)
        #pragma unroll
        for (int nb = 0; nb < 4; ++nb)
            acc[rg][nb] = (f32x4){0.f, 0.f, 0.f, 0.f};

    #pragma unroll
    for (int kc = 0; kc < 4; ++kc) {
        const int kb = kc * 32 + koff;
        float4 a00 = *reinterpret_cast<const float4*>(Ar0 + kb);
        float4 a01 = *reinterpret_cast<const float4*>(Ar0 + kb + 4);
        float4 a10 = *reinterpret_cast<const float4*>(Ar1 + kb);
        float4 a11 = *reinterpret_cast<const float4*>(Ar1 + kb + 4);
        short8 h0, l0, h1, l1;
        cvt_a8(a00, a01, h0, l0);
        cvt_a8(a10, a11, h1, l1);
        #pragma unroll
        for (int nb = 0; nb < 4; ++nb) {
            short8 whi = *reinterpret_cast<const short8*>(Wf + ((size_t)((kc * 4 + nb) * 64) + lane) * 8);
            short8 wlo = *reinterpret_cast<const short8*>(Wf + ((size_t)(1024 + (kc * 4 + nb) * 64) + lane) * 8);
            acc[0][nb] = __builtin_amdgcn_mfma_f32_16x16x32_bf16(h0, whi, acc[0][nb], 0, 0, 0);
            acc[0][nb] = __builtin_amdgcn_mfma_f32_16x16x32_bf16(l0, whi, acc[0][nb], 0, 0, 0);
            acc[0][nb] = __builtin_amdgcn_mfma_f32_16x16x32_bf16(h0, wlo, acc[0][nb], 0, 0, 0);
            acc[1][nb] = __builtin_amdgcn_mfma_f32_16x16x32_bf16(h1, whi, acc[1][nb], 0, 0, 0);
            acc[1][nb] = __builtin_amdgcn_mfma_f32_16x16x32_bf16(l1, whi, acc[1][nb], 0, 0, 0);
            acc[1][nb] = __builtin_amdgcn_mfma_f32_16x16x32_bf16(h1, wlo, acc[1][nb], 0, 0, 0);
        }
    }

    #pragma unroll
    for (int rg = 0; rg < 2; ++rg)
        #pragma unroll
        for (int nb = 0; nb < 4; ++nb)
            #pragma unroll
            for (int reg = 0; reg < 4; ++reg)
                out[(size_t)(row0w + rg * 16 + grp * 4 + reg) * 64 + nb * 16 + c] = acc[rg][nb][reg];
}

// ---------------- fused agg -> A fragments (per-lane, in registers) ---------
// zin = relu(y[n] + sum_{s in adj(n)} y[s] + bias), cols koff..+8 / 32+koff..+8
// Neighbor loop unrolled x2 for load ILP; accumulation order preserved (A,B).
__device__ __forceinline__ void agg_frag16(
    const float* __restrict__ y, const int* __restrict__ rowptr,
    const int* __restrict__ srcs, const float* __restrict__ bias,
    int n, int koff, bool valid, short8 fh[2], short8 fl[2])
{
    if (!valid) {
        #pragma unroll
        for (int i = 0; i < 8; ++i) {
            fh[0][i] = 0; fl[0][i] = 0; fh[1][i] = 0; fl[1][i] = 0;
        }
        return;
    }
    float a[16];
    {
        const float* yr = y + (size_t)n * 64;
        float4 a0 = *reinterpret_cast<const float4*>(yr + koff);
        float4 a1 = *reinterpret_cast<const float4*>(yr + koff + 4);
        float4 a2 = *reinterpret_cast<const float4*>(yr + 32 + koff);
        float4 a3 = *reinterpret_cast<const float4*>(yr + 32 + koff + 4);
        float4 b0 = *reinterpret_cast<const float4*>(bias + koff);
        float4 b1 = *reinterpret_cast<const float4*>(bias + koff + 4);
        float4 b2 = *reinterpret_cast<const float4*>(bias + 32 + koff);
        float4 b3 = *reinterpret_cast<const float4*>(bias + 32 + koff + 4);
        a[0] = a0.x + b0.x;  a[1] = a0.y + b0.y;  a[2] = a0.z + b0.z;  a[3] = a0.w + b0.w;
        a[4] = a1.x + b1.x;  a[5] = a1.y + b1.y;  a[6] = a1.z + b1.z;  a[7] = a1.w + b1.w;
        a[8] = a2.x + b2.x;  a[9] = a2.y + b2.y;  a[10] = a2.z + b2.z; a[11] = a2.w + b2.w;
        a[12] = a3.x + b3.x; a[13] = a3.y + b3.y; a[14] = a3.z + b3.z; a[15] = a3.w + b3.w;
    }
    int s0 = rowptr[n], s1 = rowptr[n + 1];
    int j = s0;
    for (; j + 2 <= s1; j += 2) {
        const float* ysA = y + (size_t)srcs[j] * 64;
        const float* ysB = y + (size_t)srcs[j + 1] * 64;
        float4 A0 = *reinterpret_cast<const float4*>(ysA + koff);
        float4 A1 = *reinterpret_cast<const float4*>(ysA + koff + 4);
        float4 A2 = *reinterpret_cast<const float4*>(ysA + 32 + koff);
        float4 A3 = *reinterpret_cast<const float4*>(ysA + 32 + koff + 4);
        float4 B0 = *reinterpret_cast<const float4*>(ysB + koff);
        float4 B1 = *reinterpret_cast<const float4*>(ysB + koff + 4);
        float4 B2 = *reinterpret_cast<const float4*>(ysB + 32 + koff);
        float4 B3 = *reinterpret_cast<const float4*>(ysB + 32 + koff + 4);
        a[0] += A0.x;  a[1] += A0.y;  a[2] += A0.z;  a[3] += A0.w;
        a[4] += A1.x;  a[5] += A1.y;  a[6] += A1.z;  a[7] += A1.w;
        a[8] += A2.x;  a[9] += A2.y;  a[10] += A2.z; a[11] += A2.w;
        a[12] += A3.x; a[13] += A3.y; a[14] += A3.z; a[15] += A3.w;
        a[0] += B0.x;  a[1] += B0.y;  a[2] += B0.z;  a[3] += B0.w;
        a[4] += B1.x;  a[5] += B1.y;  a[6] += B1.z;  a[7] += B1.w;
        a[8] += B2.x;  a[9] += B2.y;  a[10] += B2.z; a[11] += B2.w;
        a[12] += B3.x; a[13] += B3.y; a[14] += B3.z; a[15] += B3.w;
    }
    if (j < s1) {
        const float* ys = y + (size_t)srcs[j] * 64;
        float4 v0 = *reinterpret_cast<const float4*>(ys + koff);
        float4 v1 = *reinterpret_cast<const float4*>(ys + koff + 4);
        float4 v2 = *reinterpret_cast<const float4*>(ys + 32 + koff);
        float4 v3 = *reinterpret_cast<const float4*>(ys + 32 + koff + 4);
        a[0] += v0.x;  a[1] += v0.y;  a[2] += v0.z;  a[3] += v0.w;
        a[4] += v1.x;  a[5] += v1.y;  a[6] += v1.z;  a[7] += v1.w;
        a[8] += v2.x;  a[9] += v2.y;  a[10] += v2.z; a[11] += v2.w;
        a[12] += v3.x; a[13] += v3.y; a[14] += v3.z; a[15] += v3.w;
    }
    #pragma unroll
    for (int i = 0; i < 16; ++i) {
        float v = fmaxf(a[i], 0.f);
        unsigned short h = f2bf(v);
        float r = v - bf2f(h);
        fh[i >> 3][i & 7] = (short)h;
        fl[i >> 3][i & 7] = (short)f2bf(r);
    }
}

// ---------------- mmaggmm: y2 = relu(agg(y1)@W1b+b1b)@W2a ----------------
__global__ __launch_bounds__(256) void mmaggmm_k(
    const float* __restrict__ y, const int* __restrict__ rowptr,
    const int* __restrict__ srcs, const float* __restrict__ bagg,
    const short* __restrict__ Wf1, const float* __restrict__ b1,
    const short* __restrict__ Wf2, float* __restrict__ out, int N)
{
    __shared__ short hT[4][32 * 72];
    __shared__ short lT[4][32 * 72];
    const int tid = threadIdx.x;
    const int lane = tid & 63;
    const int wv = tid >> 6;
    const int row0w = blockIdx.x * 128 + wv * 32;
    const int grp = lane >> 4, c = lane & 15;
    const int koff = grp * 8;

    short8 fh0[2], fl0[2], fh1[2], fl1[2];
    {
        int n0 = row0w + c;
        int n1 = row0w + 16 + c;
        agg_frag16(y, rowptr, srcs, bagg, n0, koff, n0 < N, fh0, fl0);
        agg_frag16(y, rowptr, srcs, bagg, n1, koff, n1 < N, fh1, fl1);
    }

    f32x4 acc[2][4];
    #pragma unroll
    for (int rg = 0; rg < 2; ++rg)
        #pragma unroll
        for (int nb = 0; nb < 4; ++nb)
            acc[rg][nb] = (f32x4){0.f, 0.f, 0.f, 0.f};

    #pragma unroll
    for (int kc = 0; kc < 2; ++kc) {
        #pragma unroll
        for (int nb = 0; nb < 4; ++nb) {
            short8 whi = *reinterpret_cast<const short8*>(Wf1 + ((size_t)((kc * 4 + nb) * 64) + lane) * 8);
            short8 wlo = *reinterpret_cast<const short8*>(Wf1 + ((size_t)(512 + (kc * 4 + nb) * 64) + lane) * 8);
            acc[0][nb] = __builtin_amdgcn_mfma_f32_16x16x32_bf16(fh0[kc], whi, acc[0][nb], 0, 0, 0);
            acc[0][nb] = __builtin_amdgcn_mfma_f32_16x16x32_bf16(fl0[kc], whi, acc[0][nb], 0, 0, 0);
            acc[0][nb] = __builtin_amdgcn_mfma_f32_16x16x32_bf16(fh0[kc], wlo, acc[0][nb], 0, 0, 0);
            acc[1][nb] = __builtin_amdgcn_mfma_f32_16x16x32_bf16(fh1[kc], whi, acc[1][nb], 0, 0, 0);
            acc[1][nb] = __builtin_amdgcn_mfma_f32_16x16x32_bf16(fl1[kc], whi, acc[1][nb], 0, 0, 0);
            acc[1][nb] = __builtin_amdgcn_mfma_f32_16x16x32_bf16(fh1[kc], wlo, acc[1][nb], 0, 0, 0);
        }
    }

    // h1 = relu(acc + b1) -> split -> per-wave LDS planes (stride 72 shorts)
    #pragma unroll
    for (int rg = 0; rg < 2; ++rg)
        #pragma unroll
        for (int nb = 0; nb < 4; ++nb) {
            const int col = nb * 16 + c;
            const float bv = b1[col];
            #pragma unroll
            for (int reg = 0; reg < 4; ++reg) {
                const int lr = rg * 16 + grp * 4 + reg;
                float v = fmaxf(acc[rg][nb][reg] + bv, 0.f);
                unsigned short h = f2bf(v);
                float r = v - bf2f(h);
                hT[wv][lr * 72 + col] = (short)h;
                lT[wv][lr * 72 + col] = (short)f2bf(r);
            }
        }
    __syncthreads();

    f32x4 acc2[2][4];
    #pragma unroll
    for (int rg = 0; rg < 2; ++rg)
        #pragma unroll
        for (int nb = 0; nb < 4; ++nb)
            acc2[rg][nb] = (f32x4){0.f, 0.f, 0.f, 0.f};

    #pragma unroll
    for (int kc = 0; kc < 2; ++kc) {
        const int kb = kc * 32 + koff;
        short8 h0 = *reinterpret_cast<const short8*>(&hT[wv][(0 + c) * 72 + kb]);
        short8 l0 = *reinterpret_cast<const short8*>(&lT[wv][(0 + c) * 72 + kb]);
        short8 h1 = *reinterpret_cast<const short8*>(&hT[wv][(16 + c) * 72 + kb]);
        short8 l1 = *reinterpret_cast<const short8*>(&lT[wv][(16 + c) * 72 + kb]);
        #pragma unroll
        for (int nb = 0; nb < 4; ++nb) {
            short8 whi = *reinterpret_cast<const short8*>(Wf2 + ((size_t)((kc * 4 + nb) * 64) + lane) * 8);
            short8 wlo = *reinterpret_cast<const short8*>(Wf2 + ((size_t)(512 + (kc * 4 + nb) * 64) + lane) * 8);
            acc2[0][nb] = __builtin_amdgcn_mfma_f32_16x16x32_bf16(h0, whi, acc2[0][nb], 0, 0, 0);
            acc2[0][nb] = __builtin_amdgcn_mfma_f32_16x16x32_bf16(l0, whi, acc2[0][nb], 0, 0, 0);
            acc2[0][nb] = __builtin_amdgcn_mfma_f32_16x16x32_bf16(h0, wlo, acc2[0][nb], 0, 0, 0);
            acc2[1][nb] = __builtin_amdgcn_mfma_f32_16x16x32_bf16(h1, whi, acc2[1][nb], 0, 0, 0);
            acc2[1][nb] = __builtin_amdgcn_mfma_f32_16x16x32_bf16(l1, whi, acc2[1][nb], 0, 0, 0);
            acc2[1][nb] = __builtin_amdgcn_mfma_f32_16x16x32_bf16(h1, wlo, acc2[1][nb], 0, 0, 0);
        }
    }

    #pragma unroll
    for (int rg = 0; rg < 2; ++rg)
        #pragma unroll
        for (int nb = 0; nb < 4; ++nb)
            #pragma unroll
            for (int reg = 0; reg < 4; ++reg)
                out[(size_t)(row0w + rg * 16 + grp * 4 + reg) * 64 + nb * 16 + c] = acc2[rg][nb][reg];
}

// ---------------- mmaggpool: relu(agg(y2)@W2b+b2b).fcW -> atomics ----------
__global__ __launch_bounds__(256) void mmaggpool_k(
    const float* __restrict__ y, const int* __restrict__ rowptr,
    const int* __restrict__ srcs, const float* __restrict__ bagg,
    const short* __restrict__ Wf, const float* __restrict__ bias,
    const float* __restrict__ fcW, const int* __restrict__ batch,
    float* __restrict__ gacc, int N)
{
    __shared__ float rd[4][32];
    __shared__ int bls[4][32];
    const int tid = threadIdx.x;
    const int lane = tid & 63;
    const int wv = tid >> 6;
    const int row0w = blockIdx.x * 128 + wv * 32;
    const int grp = lane >> 4, c = lane & 15;
    const int koff = grp * 8;

    if (lane < 32) bls[wv][lane] = batch[min(row0w + lane, N - 1)];

    short8 fh0[2], fl0[2], fh1[2], fl1[2];
    {
        int n0 = row0w + c;
        int n1 = row0w + 16 + c;
        agg_frag16(y, rowptr, srcs, bagg, n0, koff, n0 < N, fh0, fl0);
        agg_frag16(y, rowptr, srcs, bagg, n1, koff, n1 < N, fh1, fl1);
    }

    f32x4 acc[2][4];
    #pragma unroll
    for (int rg = 0; rg < 2; ++rg)
        #pragma unroll
        for (int nb = 0; nb < 4; ++nb)
            acc[rg][nb] = (f32x4){0.f, 0.f, 0.f, 0.f};

    #pragma unroll
    for (int kc = 0; kc < 2; ++kc) {
        #pragma unroll
        for (int nb = 0; nb < 4; ++nb) {
            short8 whi = *reinterpret_cast<const short8*>(Wf + ((size_t)((kc * 4 + nb) * 64) + lane) * 8);
            short8 wlo = *reinterpret_cast<const short8*>(Wf + ((size_t)(512 + (kc * 4 + nb) * 64) + lane) * 8);
            acc[0][nb] = __builtin_amdgcn_mfma_f32_16x16x32_bf16(fh0[kc], whi, acc[0][nb], 0, 0, 0);
            acc[0][nb] = __builtin_amdgcn_mfma_f32_16x16x32_bf16(fl0[kc], whi, acc[0][nb], 0, 0, 0);
            acc[0][nb] = __builtin_amdgcn_mfma_f32_16x16x32_bf16(fh0[kc], wlo, acc[0][nb], 0, 0, 0);
            acc[1][nb] = __builtin_amdgcn_mfma_f32_16x16x32_bf16(fh1[kc], whi, acc[1][nb], 0, 0, 0);
            acc[1][nb] = __builtin_amdgcn_mfma_f32_16x16x32_bf16(fl1[kc], whi, acc[1][nb], 0, 0, 0);
            acc[1][nb] = __builtin_amdgcn_mfma_f32_16x16x32_bf16(fh1[kc], wlo, acc[1][nb], 0, 0, 0);
        }
    }

    float bv[4], fw[4];
    #pragma unroll
    for (int nb = 0; nb < 4; ++nb) {
        bv[nb] = bias[nb * 16 + c];
        fw[nb] = fcW[nb * 16 + c];
    }

    #pragma unroll
    for (int rg = 0; rg < 2; ++rg)
        #pragma unroll
        for (int reg = 0; reg < 4; ++reg) {
            float t = 0.f;
            #pragma unroll
            for (int nb = 0; nb < 4; ++nb)
                t += fmaxf(acc[rg][nb][reg] + bv[nb], 0.f) * fw[nb];
            t += __shfl_xor(t, 1, 16);
            t += __shfl_xor(t, 2, 16);
            t += __shfl_xor(t, 4, 16);
            t += __shfl_xor(t, 8, 16);
            if (c == 0) rd[wv][rg * 16 + grp * 4 + reg] = t;
        }

    if (lane == 0) {
        int cnt = min(32, N - row0w);
        if (cnt > 0) {
            int curg = bls[wv][0];
            float s = rd[wv][0];
            for (int i = 1; i < cnt; ++i) {
                int g = bls[wv][i];
                float v = rd[wv][i];
                if (g == curg) s += v;
                else { atomicAdd(&gacc[curg], s); curg = g; s = v; }
            }
            atomicAdd(&gacc[curg], s);
        }
    }
}

// ---------------- finalize ----------------
__global__ __launch_bounds__(256) void finalize_k(
    const float* __restrict__ gacc, const int* __restrict__ batch,
    const float* __restrict__ fcb, float* __restrict__ out, int N, int G)
{
    int g = blockIdx.x * 256 + threadIdx.x;
    if (g >= G) return;
    int lo = 0, hi = N;
    while (lo < hi) { int m = (lo + hi) >> 1; if (batch[m] < g) lo = m + 1; else hi = m; }
    int start = lo;
    hi = N;
    while (lo < hi) { int m = (lo + hi) >> 1; if (batch[m] < g + 1) lo = m + 1; else hi = m; }
    float cnt = fmaxf((float)(lo - start), 1.f);
    out[g] = gacc[g] / cnt + fcb[0];
}

extern "C" void kernel_launch(void* const* d_in, const int* in_sizes, int n_in,
                              void* d_out, int out_size, void* d_ws, size_t ws_size,
                              hipStream_t stream)
{
    const float* x     = (const float*)d_in[0];
    const int*   ei    = (const int*)d_in[1];
    const int*   batch = (const int*)d_in[2];
    const float* W1a   = (const float*)d_in[3];
    const float* b1a   = (const float*)d_in[4];
    const float* W1b   = (const float*)d_in[5];
    const float* b1b   = (const float*)d_in[6];
    const float* W2a   = (const float*)d_in[7];
    const float* b2a   = (const float*)d_in[8];
    const float* W2b   = (const float*)d_in[9];
    const float* b2b   = (const float*)d_in[10];
    const float* fcW   = (const float*)d_in[11];
    const float* fcb   = (const float*)d_in[12];
    float* out = (float*)d_out;

    const int N = NODES, E = EDGES, G = GRAPHS;
    char* ws = (char*)d_ws;

    float* y1 = (float*)ws;                                    // NPAD*64 f32
    float* y2 = (float*)(ws + (size_t)NPAD * 64 * 4);          // NPAD*64 f32
    char*  rest = ws + 2 * (size_t)NPAD * 64 * 4;
    int* cnt    = (int*)rest;            // N
    int* rowptr = cnt + NODES;           // N+1
    int* cursor = rowptr + NODES + 1;    // N
    int* srcs   = cursor + NODES;        // E
    int* bsum   = srcs + EDGES;          // NB_SCAN
    float* gacc = (float*)(bsum + NB_SCAN + 2);                // G
    short* F1a  = (short*)(((size_t)(gacc + GRAPHS) + 63) & ~(size_t)63);
    short* F1b  = F1a + 2 * 1024 * 8;
    short* F2a  = F1b + 2 * 512 * 8;
    short* F2b  = F2a + 2 * 512 * 8;

    const int NBLK = NPAD / 128;   // 1563

    // ---- setup (zero cnt/gacc + weight fragments) + CSR build ----
    setup_k<<<NB_SCAN, 256, 0, stream>>>(W1a, W1b, W2a, W2b, F1a, F1b, F2a, F2b, cnt, gacc);
    count_k<<<NB_SCAN, 256, 0, stream>>>(ei, cnt, E);
    scan1_k<<<NB_SCAN, 256, 0, stream>>>(cnt, rowptr, bsum, N);
    scan23_k<<<NB_SCAN, 256, 0, stream>>>(rowptr, bsum, cursor, N, E);
    fill_k<<<NB_SCAN, 256, 0, stream>>>(ei, cursor, srcs, E);

    // ---- layer 1 GEMM ----
    mm1_k<<<NBLK, 256, 0, stream>>>(x, F1a, y1, N);

    // ---- agg1 + h1-GEMM + y2-GEMM (fused) ----
    mmaggmm_k<<<NBLK, 256, 0, stream>>>(y1, rowptr, srcs, b1a, F1b, b1b, F2a, y2, N);

    // ---- agg2 + h2-GEMM + pool (fused) ----
    mmaggpool_k<<<NBLK, 256, 0, stream>>>(y2, rowptr, srcs, b2a, F2b, b2b, fcW, batch, gacc, N);
    finalize_k<<<(G + 255) / 256, 256, 0, stream>>>(gacc, batch, fcb, out, N, G);
}